// Round 6
// baseline (300.268 us; speedup 1.0000x reference)
//
#include <hip/hip_runtime.h>
#include <hip/hip_bf16.h>
#include <math.h>

typedef __hip_bfloat16 bf16;
typedef __attribute__((ext_vector_type(4))) float v_f32x4;
typedef __attribute__((ext_vector_type(4))) unsigned short v_u16x4;
typedef __attribute__((ext_vector_type(8))) unsigned short v_u16x8;
typedef __attribute__((ext_vector_type(8))) __bf16 v_bf16x8;

#define NB 2
#define NT 2048
#define ND 1024
#define NH 16
#define NSC 64
#define NST 16
#define NM (NB*NT)
#define RMS_EPS 1.1920929e-07f
#define NCHUNK 32
#define CLEN 64

__device__ inline float b2f(unsigned short u) {
  union { unsigned int i; float f; } v; v.i = ((unsigned int)u) << 16; return v.f;
}
__device__ inline unsigned short f2b(float f) {  // RNE f32->bf16
  union { float f; unsigned int i; } v; v.f = f;
  unsigned int r = (v.i + 0x7FFF + ((v.i >> 16) & 1)) >> 16;
  return (unsigned short)r;
}

// async global->LDS, 16B per lane; LDS dest = wave-uniform base + lane*16
__device__ inline void gl_lds16(const bf16* g, bf16* l) {
  __builtin_amdgcn_global_load_lds((__attribute__((address_space(1))) void*)g,
                                   (__attribute__((address_space(3))) void*)l,
                                   16, 0, 0);
}

// ---------------- fused f32 -> bf16 conversion of ALL weights (one launch) ----------------
// block -> segment map (1024 f32 per block):
//   [0,3072)   qkv_w -> qkvw_b        [3072,4096) o_w -> ow_b
//   [4096,4160) out_w -> outw_b       [4160,4224) in_w -> W1[0:]
//   [4224,4288) gate_w -> W1[65536:]  [4288,4292) dt_w -> W2[0:]
//   4292 Bp_w -> W2[4096:]            4293 Cp_w -> W2[5120:]
//   4294: zero W2[6144:8192]
__global__ __launch_bounds__(256) void cvt_all_kernel(
    const float* __restrict__ qkv_w, const float* __restrict__ o_w,
    const float* __restrict__ out_w, const float* __restrict__ in_w,
    const float* __restrict__ gate_w, const float* __restrict__ dt_w,
    const float* __restrict__ Bp_w, const float* __restrict__ Cp_w,
    bf16* __restrict__ qkvw_b, bf16* __restrict__ ow_b, bf16* __restrict__ outw_b,
    bf16* __restrict__ W1, bf16* __restrict__ W2) {
  const int blk = blockIdx.x, t = threadIdx.x;
  const float* src; bf16* dst; int base;
  if (blk < 3072)      { src = qkv_w;  dst = qkvw_b;      base = blk; }
  else if (blk < 4096) { src = o_w;    dst = ow_b;        base = blk - 3072; }
  else if (blk < 4160) { src = out_w;  dst = outw_b;      base = blk - 4096; }
  else if (blk < 4224) { src = in_w;   dst = W1;          base = blk - 4160; }
  else if (blk < 4288) { src = gate_w; dst = W1 + 65536;  base = blk - 4224; }
  else if (blk < 4292) { src = dt_w;   dst = W2;          base = blk - 4288; }
  else if (blk == 4292){ src = Bp_w;   dst = W2 + 4096;   base = 0; }
  else if (blk == 4293){ src = Cp_w;   dst = W2 + 5120;   base = 0; }
  else {  // zero tail of W2
    v_u16x8 z;
    #pragma unroll
    for (int i = 0; i < 8; i++) z[i] = 0;
    *(v_u16x8*)(W2 + 6144 + t * 8) = z;
    return;
  }
  int i = base * 256 + t;
  v_f32x4 v = ((const v_f32x4*)src)[i];
  v_u16x4 o;
  o[0] = f2b(v[0]); o[1] = f2b(v[1]); o[2] = f2b(v[2]); o[3] = f2b(v[3]);
  ((v_u16x4*)dst)[i] = o;
}

// ---------------- RMSNorm: f32 in, f32 weight, bf16 out ----------------
__global__ __launch_bounds__(256) void rmsnorm_kernel(
    const float* __restrict__ x, const float* __restrict__ w, bf16* __restrict__ out) {
  const int row = blockIdx.x;
  const int t = threadIdx.x;
  v_f32x4 xv = *(const v_f32x4*)(x + (size_t)row * ND + t * 4);
  float s = xv[0]*xv[0] + xv[1]*xv[1] + xv[2]*xv[2] + xv[3]*xv[3];
  #pragma unroll
  for (int off = 32; off; off >>= 1) s += __shfl_xor(s, off, 64);
  __shared__ float red[4];
  __shared__ float scale_s;
  if ((t & 63) == 0) red[t >> 6] = s;
  __syncthreads();
  if (t == 0) {
    float tot = red[0] + red[1] + red[2] + red[3];
    scale_s = rsqrtf(tot * (1.0f / ND) + RMS_EPS);
  }
  __syncthreads();
  float sc = scale_s;
  v_f32x4 wv = *(const v_f32x4*)(w + t * 4);
  unsigned short* orow = (unsigned short*)out + (size_t)row * ND + t * 4;
  v_u16x4 o;
  o[0] = f2b(xv[0] * sc * wv[0]);
  o[1] = f2b(xv[1] * sc * wv[1]);
  o[2] = f2b(xv[2] * sc * wv[2]);
  o[3] = f2b(xv[3] * sc * wv[3]);
  *(v_u16x4*)orow = o;
}

// ---------------- GEMM 128x128: C[M,N] = A[M,K(lda)] @ Bw[N,K]^T ----------------
template <bool RES, bool OUTF32>
__global__ __launch_bounds__(256) void gemm_bt_kernel(
    const bf16* __restrict__ A, const bf16* __restrict__ Bw,
    const float* __restrict__ res, void* __restrict__ Cout, int N, int K, int lda) {
  __shared__ alignas(16) bf16 As[128 * 32];
  __shared__ alignas(16) bf16 Bs[128 * 32];
  const int tid = threadIdx.x;
  const int wid = tid >> 6;
  const int lane = tid & 63;
  const int c = lane & 15;
  const int quad = lane >> 4;
  const int m0 = blockIdx.y * 128;
  const int n0 = blockIdx.x * 128;
  const int wm = (wid >> 1) * 64;
  const int wn = (wid & 1) * 64;
  const int srow = tid >> 2;
  const int schunk = tid & 3;

  const bf16* Ap0 = A + (size_t)(m0 + srow) * lda + schunk * 8;
  const bf16* Ap1 = Ap0 + (size_t)64 * lda;
  const bf16* Bp0 = Bw + (size_t)(n0 + srow) * K + schunk * 8;
  const bf16* Bp1 = Bp0 + (size_t)64 * K;
  bf16* AsW0 = As + wid * 512;
  bf16* AsW1 = As + 2048 + wid * 512;
  bf16* BsW0 = Bs + wid * 512;
  bf16* BsW1 = Bs + 2048 + wid * 512;

  v_f32x4 acc[4][4];
  #pragma unroll
  for (int i = 0; i < 4; i++)
    #pragma unroll
    for (int j = 0; j < 4; j++)
      #pragma unroll
      for (int r = 0; r < 4; r++) acc[i][j][r] = 0.0f;

  const int nk = K >> 5;
  for (int kt = 0; kt < nk; kt++) {
    gl_lds16(Ap0 + kt * 32, AsW0);
    gl_lds16(Ap1 + kt * 32, AsW1);
    gl_lds16(Bp0 + kt * 32, BsW0);
    gl_lds16(Bp1 + kt * 32, BsW1);
    __syncthreads();
    v_bf16x8 af[4], bfw[4];
    #pragma unroll
    for (int i = 0; i < 4; i++)
      af[i] = *(const v_bf16x8*)&As[(wm + i * 16 + c) * 32 + quad * 8];
    #pragma unroll
    for (int j = 0; j < 4; j++)
      bfw[j] = *(const v_bf16x8*)&Bs[(wn + j * 16 + c) * 32 + quad * 8];
    #pragma unroll
    for (int i = 0; i < 4; i++)
      #pragma unroll
      for (int j = 0; j < 4; j++)
        acc[i][j] = __builtin_amdgcn_mfma_f32_16x16x32_bf16(af[i], bfw[j], acc[i][j], 0, 0, 0);
    __syncthreads();
  }

  #pragma unroll
  for (int i = 0; i < 4; i++)
    #pragma unroll
    for (int j = 0; j < 4; j++)
      #pragma unroll
      for (int r = 0; r < 4; r++) {
        int rg = m0 + wm + i * 16 + quad * 4 + r;
        int cg = n0 + wn + j * 16 + c;
        size_t idx = (size_t)rg * N + cg;
        float v = acc[i][j][r];
        if (RES) v += res[idx];
        if (OUTF32) ((float*)Cout)[idx] = v;
        else ((bf16*)Cout)[idx] = __float2bfloat16(v);
      }
}

// ---------------- GEMM 64x128 (more blocks for small-M/N shapes) ----------------
template <bool RES, bool OUTF32>
__global__ __launch_bounds__(256) void gemm_bt64_kernel(
    const bf16* __restrict__ A, const bf16* __restrict__ Bw,
    const float* __restrict__ res, void* __restrict__ Cout, int N, int K, int lda) {
  __shared__ alignas(16) bf16 As[64 * 32];
  __shared__ alignas(16) bf16 Bs[128 * 32];
  const int tid = threadIdx.x;
  const int wid = tid >> 6;
  const int lane = tid & 63;
  const int c = lane & 15;
  const int quad = lane >> 4;
  const int m0 = blockIdx.y * 64;
  const int n0 = blockIdx.x * 128;
  const int wm = (wid & 1) * 32;
  const int wn = (wid >> 1) * 64;
  const int srow = tid >> 2;
  const int schunk = tid & 3;

  const bf16* Ap = A + (size_t)(m0 + srow) * lda + schunk * 8;
  const bf16* Bp0 = Bw + (size_t)(n0 + srow) * K + schunk * 8;
  const bf16* Bp1 = Bp0 + (size_t)64 * K;
  bf16* AsW  = As + wid * 512;
  bf16* BsW0 = Bs + wid * 512;
  bf16* BsW1 = Bs + 2048 + wid * 512;

  v_f32x4 acc[2][4];
  #pragma unroll
  for (int i = 0; i < 2; i++)
    #pragma unroll
    for (int j = 0; j < 4; j++)
      #pragma unroll
      for (int r = 0; r < 4; r++) acc[i][j][r] = 0.0f;

  const int nk = K >> 5;
  for (int kt = 0; kt < nk; kt++) {
    gl_lds16(Ap + kt * 32, AsW);
    gl_lds16(Bp0 + kt * 32, BsW0);
    gl_lds16(Bp1 + kt * 32, BsW1);
    __syncthreads();
    v_bf16x8 af[2], bfw[4];
    #pragma unroll
    for (int i = 0; i < 2; i++)
      af[i] = *(const v_bf16x8*)&As[(wm + i * 16 + c) * 32 + quad * 8];
    #pragma unroll
    for (int j = 0; j < 4; j++)
      bfw[j] = *(const v_bf16x8*)&Bs[(wn + j * 16 + c) * 32 + quad * 8];
    #pragma unroll
    for (int i = 0; i < 2; i++)
      #pragma unroll
      for (int j = 0; j < 4; j++)
        acc[i][j] = __builtin_amdgcn_mfma_f32_16x16x32_bf16(af[i], bfw[j], acc[i][j], 0, 0, 0);
    __syncthreads();
  }

  #pragma unroll
  for (int i = 0; i < 2; i++)
    #pragma unroll
    for (int j = 0; j < 4; j++)
      #pragma unroll
      for (int r = 0; r < 4; r++) {
        int rg = m0 + wm + i * 16 + quad * 4 + r;
        int cg = n0 + wn + j * 16 + c;
        size_t idx = (size_t)rg * N + cg;
        float v = acc[i][j][r];
        if (RES) v += res[idx];
        if (OUTF32) ((float*)Cout)[idx] = v;
        else ((bf16*)Cout)[idx] = __float2bfloat16(v);
      }
}

// ---------------- skinny GEMM: C[M,128] = A[M,K(lda)] @ Bw[128,K]^T, M-tile 16 ----------------
template <bool OUTF32>
__global__ __launch_bounds__(256) void gemm_skinny_kernel(
    const bf16* __restrict__ A, const bf16* __restrict__ Bw,
    void* __restrict__ Cout, int K, int lda) {
  __shared__ alignas(16) bf16 As[16 * 32];
  __shared__ alignas(16) bf16 Bs[128 * 32];
  const int tid = threadIdx.x;
  const int w = tid >> 6;
  const int lane = tid & 63;
  const int c = lane & 15;
  const int quad = lane >> 4;
  const int m0 = blockIdx.x * 16;
  const int lrow = lane >> 2, lchunk = lane & 3;

  const bf16* ApL = A + (size_t)(m0 + lrow) * lda + lchunk * 8;
  const bf16* BpL0 = Bw + (size_t)(w * 16 + lrow) * K + lchunk * 8;
  const bf16* BpL1 = Bw + (size_t)(64 + w * 16 + lrow) * K + lchunk * 8;
  bf16* BsW0 = Bs + w * 512;
  bf16* BsW1 = Bs + 2048 + w * 512;

  v_f32x4 acc[2];
  #pragma unroll
  for (int j = 0; j < 2; j++)
    #pragma unroll
    for (int r = 0; r < 4; r++) acc[j][r] = 0.0f;

  const int nk = K >> 5;
  for (int kt = 0; kt < nk; kt++) {
    if (w == 0) gl_lds16(ApL + kt * 32, As);
    gl_lds16(BpL0 + kt * 32, BsW0);
    gl_lds16(BpL1 + kt * 32, BsW1);
    __syncthreads();
    v_bf16x8 af = *(const v_bf16x8*)&As[c * 32 + quad * 8];
    #pragma unroll
    for (int j = 0; j < 2; j++) {
      v_bf16x8 bfw = *(const v_bf16x8*)&Bs[(w * 32 + j * 16 + c) * 32 + quad * 8];
      acc[j] = __builtin_amdgcn_mfma_f32_16x16x32_bf16(af, bfw, acc[j], 0, 0, 0);
    }
    __syncthreads();
  }

  #pragma unroll
  for (int j = 0; j < 2; j++)
    #pragma unroll
    for (int r = 0; r < 4; r++) {
      size_t idx = (size_t)(m0 + quad * 4 + r) * 128 + w * 32 + j * 16 + c;
      if (OUTF32) ((float*)Cout)[idx] = acc[j][r];
      else ((bf16*)Cout)[idx] = __float2bfloat16(acc[j][r]);
    }
}

// ---------------- V transpose: qkv V-part -> VtG[bh][d][t] ----------------
__global__ __launch_bounds__(256) void vtrans_kernel(const bf16* __restrict__ qkv,
                                                     bf16* __restrict__ VtG) {
  __shared__ alignas(16) bf16 Vs[64 * 72];
  const int tid = threadIdx.x;
  const int t0 = blockIdx.x * 64;
  const int bh = blockIdx.y;
  const int b = bh >> 4, h = bh & 15;
  const int srow = tid >> 2, schunk = tid & 3;
  {
    const bf16* src = qkv + (size_t)(b * NT + t0 + srow) * 3072 + 2048 + h * 64 + schunk * 16;
    *(v_u16x8*)&Vs[srow * 72 + schunk * 16] = *(const v_u16x8*)src;
    *(v_u16x8*)&Vs[srow * 72 + schunk * 16 + 8] = *(const v_u16x8*)(src + 8);
  }
  __syncthreads();
  const unsigned short* Vsu = (const unsigned short*)Vs;
  v_u16x8 a, bvec;
  #pragma unroll
  for (int i = 0; i < 8; i++) a[i] = Vsu[(schunk * 16 + i) * 72 + srow];
  #pragma unroll
  for (int i = 0; i < 8; i++) bvec[i] = Vsu[(schunk * 16 + 8 + i) * 72 + srow];
  bf16* dst = VtG + (size_t)(bh * 64 + srow) * NT + t0 + schunk * 16;
  *(v_u16x8*)dst = a;
  *(v_u16x8*)(dst + 8) = bvec;
}

// ---------------- Flash attention (causal), Q-tile 128, no-max softmax ----------------
__global__ __launch_bounds__(256) void attn_kernel(const bf16* __restrict__ qkv,
                                                   const bf16* __restrict__ VtG,
                                                   bf16* __restrict__ out) {
  __shared__ alignas(16) bf16 Qs[128 * 72];
  __shared__ alignas(16) bf16 Ks[64 * 72];
  __shared__ alignas(16) bf16 Vt[64 * 72];
  __shared__ alignas(16) bf16 Ps[128 * 72];
  const int tid = threadIdx.x;
  const int w = tid >> 6;
  const int lane = tid & 63;
  const int c = lane & 15;
  const int quad = lane >> 4;
  // 512 blocks; blocks id and id+256 land on the same CU (round-robin) and
  // pair qt2 = x with 15-x -> constant 34 iterations per CU.
  const int id = blockIdx.x;
  const int bh = id & 31;
  const int j5 = id >> 5;          // 0..15
  const int qt2 = (j5 & 8) ? (15 - (j5 & 7)) : (j5 & 7);
  const int b = bh >> 4;
  const int h = bh & 15;
  const int srow = tid >> 2;
  const int schunk = tid & 3;
  const int qbase = qt2 * 128;

  #pragma unroll
  for (int g = 0; g < 2; g++) {  // stage Q tile [128 q][64 d]
    const bf16* src = qkv + (size_t)(b * NT + qbase + g * 64 + srow) * 3072 + h * 64 + schunk * 16;
    *(v_u16x8*)&Qs[(g * 64 + srow) * 72 + schunk * 16] = *(const v_u16x8*)src;
    *(v_u16x8*)&Qs[(g * 64 + srow) * 72 + schunk * 16 + 8] = *(const v_u16x8*)(src + 8);
  }
  __syncthreads();
  v_bf16x8 aq[2][2];
  #pragma unroll
  for (int g = 0; g < 2; g++) {
    aq[g][0] = *(const v_bf16x8*)&Qs[(g * 64 + w * 16 + c) * 72 + quad * 8];
    aq[g][1] = *(const v_bf16x8*)&Qs[(g * 64 + w * 16 + c) * 72 + 32 + quad * 8];
  }

  float l_part[2][4];
  v_f32x4 o[2][4];
  #pragma unroll
  for (int g = 0; g < 2; g++)
    #pragma unroll
    for (int r = 0; r < 4; r++) l_part[g][r] = 0.0f;
  #pragma unroll
  for (int g = 0; g < 2; g++)
    #pragma unroll
    for (int j = 0; j < 4; j++)
      #pragma unroll
      for (int r = 0; r < 4; r++) o[g][j][r] = 0.0f;

  const int ktmax = 2 * qt2 + 1;
  for (int kt = 0; kt <= ktmax; kt++) {
    {  // stage K [64 k][64 d] and Vt [64 d][64 k]
      const bf16* ksrc = qkv + (size_t)(b * NT + kt * 64 + srow) * 3072 + 1024 + h * 64 + schunk * 16;
      *(v_u16x8*)&Ks[srow * 72 + schunk * 16] = *(const v_u16x8*)ksrc;
      *(v_u16x8*)&Ks[srow * 72 + schunk * 16 + 8] = *(const v_u16x8*)(ksrc + 8);
      const bf16* vsrc = VtG + (size_t)(bh * 64 + srow) * NT + kt * 64 + schunk * 16;
      *(v_u16x8*)&Vt[srow * 72 + schunk * 16] = *(const v_u16x8*)vsrc;
      *(v_u16x8*)&Vt[srow * 72 + schunk * 16 + 8] = *(const v_u16x8*)(vsrc + 8);
    }
    __syncthreads();

    #pragma unroll
    for (int g = 0; g < 2; g++) {
      const int ktd = 2 * qt2 + g;
      if (kt <= ktd) {               // wave-uniform; g=0 fully masked at kt=ktmax
        const bool diag = (kt == ktd);
        #pragma unroll
        for (int j4 = 0; j4 < 4; j4++) {
          v_bf16x8 bk0 = *(const v_bf16x8*)&Ks[(j4 * 16 + c) * 72 + quad * 8];
          v_bf16x8 bk1 = *(const v_bf16x8*)&Ks[(j4 * 16 + c) * 72 + 32 + quad * 8];
          v_f32x4 z;
          #pragma unroll
          for (int r = 0; r < 4; r++) z[r] = 0.0f;
          z = __builtin_amdgcn_mfma_f32_16x16x32_bf16(aq[g][0], bk0, z, 0, 0, 0);
          z = __builtin_amdgcn_mfma_f32_16x16x32_bf16(aq[g][1], bk1, z, 0, 0, 0);
          #pragma unroll
          for (int r = 0; r < 4; r++) {
            float p = __expf(z[r] * 0.125f);
            if (diag && (j4 * 16 + c) > (w * 16 + quad * 4 + r)) p = 0.0f;
            l_part[g][r] += p;
            Ps[(g * 64 + w * 16 + quad * 4 + r) * 72 + j4 * 16 + c] = __float2bfloat16(p);
          }
        }
        #pragma unroll
        for (int ks = 0; ks < 2; ks++) {
          v_bf16x8 ap = *(const v_bf16x8*)&Ps[(g * 64 + w * 16 + c) * 72 + ks * 32 + quad * 8];
          #pragma unroll
          for (int jn = 0; jn < 4; jn++) {
            v_bf16x8 bv = *(const v_bf16x8*)&Vt[(jn * 16 + c) * 72 + ks * 32 + quad * 8];
            o[g][jn] = __builtin_amdgcn_mfma_f32_16x16x32_bf16(ap, bv, o[g][jn], 0, 0, 0);
          }
        }
      }
    }
    __syncthreads();
  }

  #pragma unroll
  for (int g = 0; g < 2; g++)
    #pragma unroll
    for (int r = 0; r < 4; r++) {
      float l = l_part[g][r];
      l += __shfl_xor(l, 1, 64);
      l += __shfl_xor(l, 2, 64);
      l += __shfl_xor(l, 4, 64);
      l += __shfl_xor(l, 8, 64);
      l_part[g][r] = l;
    }

  #pragma unroll
  for (int g = 0; g < 2; g++)
    #pragma unroll
    for (int jn = 0; jn < 4; jn++)
      #pragma unroll
      for (int r = 0; r < 4; r++) {
        int qg = qbase + g * 64 + w * 16 + quad * 4 + r;
        out[(size_t)(b * NT + qg) * ND + h * 64 + jn * 16 + c] =
            __float2bfloat16(o[g][jn][r] / l_part[g][r]);
      }
}

// ---------------- scan prep: softplus/silu/dtz from zg + P2 ----------------
__global__ __launch_bounds__(256) void scanprep_kernel(
    const bf16* __restrict__ zg, const float* __restrict__ P2, const float* __restrict__ dt_b,
    float* __restrict__ dt_a, float* __restrict__ dtz_a, float* __restrict__ gate_a) {
  const int row = blockIdx.x * 4 + (threadIdx.x >> 6);
  const int c = threadIdx.x & 63;
  const unsigned short* zgu = (const unsigned short*)zg;
  float z = b2f(zgu[(size_t)row * 128 + c]);
  float g = b2f(zgu[(size_t)row * 128 + 64 + c]);
  float a = P2[(size_t)row * 128 + c] + dt_b[c];
  float dt = (a > 20.0f) ? a : log1pf(__expf(a));
  dt_a[(size_t)row * NSC + c] = dt;
  dtz_a[(size_t)row * NSC + c] = dt * z;
  gate_a[(size_t)row * NSC + c] = g / (1.0f + __expf(-g));
}

// ---------------- chunked parallel scan ----------------
__global__ __launch_bounds__(256) void scanA_kernel(
    const float* __restrict__ dt_a, const float* __restrict__ dtz_a,
    const float* __restrict__ P2, const float* __restrict__ A_log,
    float* __restrict__ Pbuf, float* __restrict__ Sbuf) {
  __shared__ float dtS[CLEN * 16], dtzS[CLEN * 16], biS[CLEN * 16];
  const int k = blockIdx.x, scg = blockIdx.y, b = blockIdx.z;
  const int tid = threadIdx.x;
  const int t0 = k * CLEN;
  {
    int r = tid >> 2, c4 = (tid & 3) * 4;
    *(v_f32x4*)&dtS[r * 16 + c4]  = *(const v_f32x4*)&dt_a[(size_t)(b * NT + t0 + r) * NSC + scg * 16 + c4];
    *(v_f32x4*)&dtzS[r * 16 + c4] = *(const v_f32x4*)&dtz_a[(size_t)(b * NT + t0 + r) * NSC + scg * 16 + c4];
    *(v_f32x4*)&biS[r * 16 + c4]  = *(const v_f32x4*)&P2[(size_t)(b * NT + t0 + r) * 128 + 64 + c4];
  }
  __syncthreads();
  const int st = tid & 15, scl = tid >> 4;
  const float A = -__expf(A_log[(scg * 16 + scl) * NST + st]);
  float P = 1.0f, s = 0.0f;
  #pragma unroll
  for (int t = 0; t < CLEN; t++) {
    float a = fmaf(dtS[t * 16 + scl], A, 1.0f);
    float u = dtzS[t * 16 + scl] * biS[t * 16 + st];
    P *= a;
    s = fmaf(a, s, u);
  }
  size_t idx = (size_t)(b * NCHUNK + k) * 1024 + scg * 256 + tid;
  Pbuf[idx] = P;
  Sbuf[idx] = s;
}

__global__ __launch_bounds__(1024) void scanB_kernel(
    const float* __restrict__ Pbuf, const float* __restrict__ Sbuf,
    float* __restrict__ init) {
  const int b = blockIdx.x;
  const int tid = threadIdx.x;
  float P[NCHUNK], S[NCHUNK];
  #pragma unroll
  for (int kk = 0; kk < NCHUNK; kk++) {
    size_t idx = (size_t)(b * NCHUNK + kk) * 1024 + tid;
    P[kk] = Pbuf[idx];
    S[kk] = Sbuf[idx];
  }
  float s = 0.0f;
  #pragma unroll
  for (int kk = 0; kk < NCHUNK; kk++) {
    init[(size_t)(b * NCHUNK + kk) * 1024 + tid] = s;
    s = fmaf(P[kk], s, S[kk]);
  }
}

__global__ __launch_bounds__(256) void scanC_kernel(
    const float* __restrict__ dt_a, const float* __restrict__ dtz_a,
    const float* __restrict__ P2, const float* __restrict__ gate_a,
    const float* __restrict__ A_log, const float* __restrict__ init,
    bf16* __restrict__ ys) {
  __shared__ float dtS[CLEN * 16], dtzS[CLEN * 16], biS[CLEN * 16], ciS[CLEN * 16], gS[CLEN * 16];
  const int k = blockIdx.x, scg = blockIdx.y, b = blockIdx.z;
  const int tid = threadIdx.x;
  const int t0 = k * CLEN;
  {
    int r = tid >> 2, c4 = (tid & 3) * 4;
    *(v_f32x4*)&dtS[r * 16 + c4]  = *(const v_f32x4*)&dt_a[(size_t)(b * NT + t0 + r) * NSC + scg * 16 + c4];
    *(v_f32x4*)&dtzS[r * 16 + c4] = *(const v_f32x4*)&dtz_a[(size_t)(b * NT + t0 + r) * NSC + scg * 16 + c4];
    *(v_f32x4*)&biS[r * 16 + c4]  = *(const v_f32x4*)&P2[(size_t)(b * NT + t0 + r) * 128 + 64 + c4];
    *(v_f32x4*)&ciS[r * 16 + c4]  = *(const v_f32x4*)&P2[(size_t)(b * NT + t0 + r) * 128 + 80 + c4];
    *(v_f32x4*)&gS[r * 16 + c4]   = *(const v_f32x4*)&gate_a[(size_t)(b * NT + t0 + r) * NSC + scg * 16 + c4];
  }
  __syncthreads();
  const int st = tid & 15, scl = tid >> 4;
  const float A = -__expf(A_log[(scg * 16 + scl) * NST + st]);
  float s = init[(size_t)(b * NCHUNK + k) * 1024 + scg * 256 + tid];
  for (int t = 0; t < CLEN; t++) {
    float a = fmaf(dtS[t * 16 + scl], A, 1.0f);
    float u = dtzS[t * 16 + scl] * biS[t * 16 + st];
    s = fmaf(a, s, u);
    float pv = s * ciS[t * 16 + st];
    pv += __shfl_xor(pv, 1, 64);
    pv += __shfl_xor(pv, 2, 64);
    pv += __shfl_xor(pv, 4, 64);
    pv += __shfl_xor(pv, 8, 64);
    if (st == 0)
      ys[(size_t)(b * NT + t0 + t) * NSC + scg * 16 + scl] = __float2bfloat16(pv * gS[t * 16 + scl]);
  }
}

extern "C" void kernel_launch(void* const* d_in, const int* in_sizes, int n_in,
                              void* d_out, int out_size, void* d_ws, size_t ws_size,
                              hipStream_t stream) {
  const float* x      = (const float*)d_in[0];
  const float* qkv_w  = (const float*)d_in[1];
  const float* o_w    = (const float*)d_in[2];
  const float* n1w    = (const float*)d_in[3];
  const float* n2w    = (const float*)d_in[4];
  const float* in_w   = (const float*)d_in[5];
  const float* out_w  = (const float*)d_in[6];
  const float* A_log  = (const float*)d_in[7];
  const float* Bp_w   = (const float*)d_in[8];
  const float* Cp_w   = (const float*)d_in[9];
  const float* dt_w   = (const float*)d_in[10];
  const float* dt_b   = (const float*)d_in[11];
  const float* gate_w = (const float*)d_in[12];
  float* out = (float*)d_out;

  char* ws = (char*)d_ws;
  size_t off = 0;
  auto alloc = [&](size_t bytes) {
    char* p = ws + off;
    off += (bytes + 255) & ~(size_t)255;
    return p;
  };
  bf16* qkvw_b = (bf16*)alloc((size_t)3 * ND * ND * 2);
  bf16* ow_b   = (bf16*)alloc((size_t)ND * ND * 2);
  bf16* outw_b = (bf16*)alloc((size_t)ND * NSC * 2);
  bf16* W1     = (bf16*)alloc((size_t)128 * ND * 2);
  bf16* W2     = (bf16*)alloc((size_t)128 * NSC * 2);
  char* region0 = alloc((size_t)NM * 3 * ND * 2);         // qkv bf16 -> x1 f32
  char* region1 = alloc((size_t)NM * ND * 2);             // h -> attnout -> h2
  bf16* VtG    = (bf16*)alloc((size_t)NB * NH * 64 * NT * 2);
  bf16*  zg    = (bf16*)alloc((size_t)NM * 128 * 2);
  float* P2    = (float*)alloc((size_t)NM * 128 * 4);
  float* dt_a  = (float*)alloc((size_t)NM * NSC * 4);
  float* dtz_a = (float*)alloc((size_t)NM * NSC * 4);
  float* gate_a= (float*)alloc((size_t)NM * NSC * 4);
  bf16*  ys    = (bf16*)alloc((size_t)NM * NSC * 2);
  float* Pbuf  = (float*)alloc((size_t)NB * NCHUNK * 1024 * 4);
  float* Sbuf  = (float*)alloc((size_t)NB * NCHUNK * 1024 * 4);
  float* initb = (float*)alloc((size_t)NB * NCHUNK * 1024 * 4);

  bf16*  qkv     = (bf16*)region0;
  float* x1      = (float*)region0;   // aliases qkv (dead after attn)
  bf16*  h       = (bf16*)region1;
  bf16*  attnout = (bf16*)region1;    // aliases h (dead after qkv gemm)
  bf16*  h2      = (bf16*)region1;    // aliases attnout (dead after o gemm)

  cvt_all_kernel<<<4295, 256, 0, stream>>>(qkv_w, o_w, out_w, in_w, gate_w, dt_w,
                                           Bp_w, Cp_w, qkvw_b, ow_b, outw_b, W1, W2);
  rmsnorm_kernel<<<NM, 256, 0, stream>>>(x, n1w, h);
  gemm_bt_kernel<false, false><<<dim3(3 * ND / 128, NM / 128), 256, 0, stream>>>(
      h, qkvw_b, nullptr, (void*)qkv, 3 * ND, ND, ND);
  vtrans_kernel<<<dim3(NT / 64, NB * NH), 256, 0, stream>>>(qkv, VtG);
  attn_kernel<<<(NT / 128) * NB * NH, 256, 0, stream>>>(qkv, VtG, attnout);
  gemm_bt64_kernel<true, true><<<dim3(ND / 128, NM / 64), 256, 0, stream>>>(
      attnout, ow_b, x, (void*)x1, ND, ND, ND);
  rmsnorm_kernel<<<NM, 256, 0, stream>>>(x1, n2w, h2);
  gemm_skinny_kernel<false><<<NM / 16, 256, 0, stream>>>(h2, W1, (void*)zg, ND, ND);
  gemm_skinny_kernel<true><<<NM / 16, 256, 0, stream>>>(zg, W2, (void*)P2, NSC, 128);
  scanprep_kernel<<<NM / 4, 256, 0, stream>>>(zg, P2, dt_b, dt_a, dtz_a, gate_a);
  scanA_kernel<<<dim3(NCHUNK, 4, NB), 256, 0, stream>>>(dt_a, dtz_a, P2, A_log, Pbuf, Sbuf);
  scanB_kernel<<<NB, 1024, 0, stream>>>(Pbuf, Sbuf, initb);
  scanC_kernel<<<dim3(NCHUNK, 4, NB), 256, 0, stream>>>(dt_a, dtz_a, P2, gate_a, A_log, initb, ys);
  gemm_bt64_kernel<true, true><<<dim3(ND / 128, NM / 64), 256, 0, stream>>>(
      ys, outw_b, x1, (void*)out, ND, NSC, NSC);
}

// Round 7
// 270.607 us; speedup vs baseline: 1.1096x; 1.1096x over previous
//
#include <hip/hip_runtime.h>
#include <hip/hip_bf16.h>
#include <math.h>

typedef __hip_bfloat16 bf16;
typedef __attribute__((ext_vector_type(4))) float v_f32x4;
typedef __attribute__((ext_vector_type(4))) unsigned short v_u16x4;
typedef __attribute__((ext_vector_type(8))) unsigned short v_u16x8;
typedef __attribute__((ext_vector_type(8))) __bf16 v_bf16x8;

#define NB 2
#define NT 2048
#define ND 1024
#define NH 16
#define NSC 64
#define NST 16
#define NM (NB*NT)
#define RMS_EPS 1.1920929e-07f
#define NCHUNK 32
#define CLEN 64

__device__ inline float b2f(unsigned short u) {
  union { unsigned int i; float f; } v; v.i = ((unsigned int)u) << 16; return v.f;
}
__device__ inline unsigned short f2b(float f) {  // RNE f32->bf16
  union { float f; unsigned int i; } v; v.f = f;
  unsigned int r = (v.i + 0x7FFF + ((v.i >> 16) & 1)) >> 16;
  return (unsigned short)r;
}

// async global->LDS, 16B per lane; LDS dest = wave-uniform base + lane*16
__device__ inline void gl_lds16(const bf16* g, bf16* l) {
  __builtin_amdgcn_global_load_lds((__attribute__((address_space(1))) void*)g,
                                   (__attribute__((address_space(3))) void*)l,
                                   16, 0, 0);
}

// ---------------- fused: all weight cvt (blocks 0..4294) + rmsnorm1 (blocks 4295..8390) ----------------
__global__ __launch_bounds__(256) void cvt_rms_kernel(
    const float* __restrict__ qkv_w, const float* __restrict__ o_w,
    const float* __restrict__ out_w, const float* __restrict__ in_w,
    const float* __restrict__ gate_w, const float* __restrict__ dt_w,
    const float* __restrict__ Bp_w, const float* __restrict__ Cp_w,
    bf16* __restrict__ qkvw_b, bf16* __restrict__ ow_b, bf16* __restrict__ outw_b,
    bf16* __restrict__ W1, bf16* __restrict__ W2,
    const float* __restrict__ x, const float* __restrict__ n1w, bf16* __restrict__ h) {
  const int blk = blockIdx.x, t = threadIdx.x;
  if (blk >= 4295) {  // rmsnorm1 of x row -> h
    const int row = blk - 4295;
    v_f32x4 xv = *(const v_f32x4*)(x + (size_t)row * ND + t * 4);
    float s = xv[0]*xv[0] + xv[1]*xv[1] + xv[2]*xv[2] + xv[3]*xv[3];
    #pragma unroll
    for (int off = 32; off; off >>= 1) s += __shfl_xor(s, off, 64);
    __shared__ float red[4];
    __shared__ float scale_s;
    if ((t & 63) == 0) red[t >> 6] = s;
    __syncthreads();
    if (t == 0) scale_s = rsqrtf((red[0] + red[1] + red[2] + red[3]) * (1.0f / ND) + RMS_EPS);
    __syncthreads();
    float sc = scale_s;
    v_f32x4 wv = *(const v_f32x4*)(n1w + t * 4);
    v_u16x4 o;
    o[0] = f2b(xv[0] * sc * wv[0]);
    o[1] = f2b(xv[1] * sc * wv[1]);
    o[2] = f2b(xv[2] * sc * wv[2]);
    o[3] = f2b(xv[3] * sc * wv[3]);
    *(v_u16x4*)((unsigned short*)h + (size_t)row * ND + t * 4) = o;
    return;
  }
  const float* src; bf16* dst; int base;
  if (blk < 3072)      { src = qkv_w;  dst = qkvw_b;      base = blk; }
  else if (blk < 4096) { src = o_w;    dst = ow_b;        base = blk - 3072; }
  else if (blk < 4160) { src = out_w;  dst = outw_b;      base = blk - 4096; }
  else if (blk < 4224) { src = in_w;   dst = W1;          base = blk - 4160; }
  else if (blk < 4288) { src = gate_w; dst = W1 + 65536;  base = blk - 4224; }
  else if (blk < 4292) { src = dt_w;   dst = W2;          base = blk - 4288; }
  else if (blk == 4292){ src = Bp_w;   dst = W2 + 4096;   base = 0; }
  else if (blk == 4293){ src = Cp_w;   dst = W2 + 5120;   base = 0; }
  else {  // zero tail of W2 (rows 96..127)
    v_u16x8 z;
    #pragma unroll
    for (int i = 0; i < 8; i++) z[i] = 0;
    *(v_u16x8*)(W2 + 6144 + t * 8) = z;
    return;
  }
  int i = base * 256 + t;
  v_f32x4 v = ((const v_f32x4*)src)[i];
  v_u16x4 o;
  o[0] = f2b(v[0]); o[1] = f2b(v[1]); o[2] = f2b(v[2]); o[3] = f2b(v[3]);
  ((v_u16x4*)dst)[i] = o;
}

// ---------------- GEMM 128x128: C[M,N] = A[M,K(lda)] @ Bw[N,K]^T ----------------
template <bool RES, bool OUTF32>
__global__ __launch_bounds__(256) void gemm_bt_kernel(
    const bf16* __restrict__ A, const bf16* __restrict__ Bw,
    const float* __restrict__ res, void* __restrict__ Cout, int N, int K, int lda) {
  __shared__ alignas(16) bf16 As[128 * 32];
  __shared__ alignas(16) bf16 Bs[128 * 32];
  const int tid = threadIdx.x;
  const int wid = tid >> 6;
  const int lane = tid & 63;
  const int c = lane & 15;
  const int quad = lane >> 4;
  const int m0 = blockIdx.y * 128;
  const int n0 = blockIdx.x * 128;
  const int wm = (wid >> 1) * 64;
  const int wn = (wid & 1) * 64;
  const int srow = tid >> 2;
  const int schunk = tid & 3;

  const bf16* Ap0 = A + (size_t)(m0 + srow) * lda + schunk * 8;
  const bf16* Ap1 = Ap0 + (size_t)64 * lda;
  const bf16* Bp0 = Bw + (size_t)(n0 + srow) * K + schunk * 8;
  const bf16* Bp1 = Bp0 + (size_t)64 * K;
  bf16* AsW0 = As + wid * 512;
  bf16* AsW1 = As + 2048 + wid * 512;
  bf16* BsW0 = Bs + wid * 512;
  bf16* BsW1 = Bs + 2048 + wid * 512;

  v_f32x4 acc[4][4];
  #pragma unroll
  for (int i = 0; i < 4; i++)
    #pragma unroll
    for (int j = 0; j < 4; j++)
      #pragma unroll
      for (int r = 0; r < 4; r++) acc[i][j][r] = 0.0f;

  const int nk = K >> 5;
  for (int kt = 0; kt < nk; kt++) {
    gl_lds16(Ap0 + kt * 32, AsW0);
    gl_lds16(Ap1 + kt * 32, AsW1);
    gl_lds16(Bp0 + kt * 32, BsW0);
    gl_lds16(Bp1 + kt * 32, BsW1);
    __syncthreads();
    v_bf16x8 af[4], bfw[4];
    #pragma unroll
    for (int i = 0; i < 4; i++)
      af[i] = *(const v_bf16x8*)&As[(wm + i * 16 + c) * 32 + quad * 8];
    #pragma unroll
    for (int j = 0; j < 4; j++)
      bfw[j] = *(const v_bf16x8*)&Bs[(wn + j * 16 + c) * 32 + quad * 8];
    #pragma unroll
    for (int i = 0; i < 4; i++)
      #pragma unroll
      for (int j = 0; j < 4; j++)
        acc[i][j] = __builtin_amdgcn_mfma_f32_16x16x32_bf16(af[i], bfw[j], acc[i][j], 0, 0, 0);
    __syncthreads();
  }

  #pragma unroll
  for (int i = 0; i < 4; i++)
    #pragma unroll
    for (int j = 0; j < 4; j++)
      #pragma unroll
      for (int r = 0; r < 4; r++) {
        int rg = m0 + wm + i * 16 + quad * 4 + r;
        int cg = n0 + wn + j * 16 + c;
        size_t idx = (size_t)rg * N + cg;
        float v = acc[i][j][r];
        if (RES) v += res[idx];
        if (OUTF32) ((float*)Cout)[idx] = v;
        else ((bf16*)Cout)[idx] = __float2bfloat16(v);
      }
}

// ---------------- GEMM 64x128 ----------------
template <bool RES, bool OUTF32>
__global__ __launch_bounds__(256) void gemm_bt64_kernel(
    const bf16* __restrict__ A, const bf16* __restrict__ Bw,
    const float* __restrict__ res, void* __restrict__ Cout, int N, int K, int lda) {
  __shared__ alignas(16) bf16 As[64 * 32];
  __shared__ alignas(16) bf16 Bs[128 * 32];
  const int tid = threadIdx.x;
  const int wid = tid >> 6;
  const int lane = tid & 63;
  const int c = lane & 15;
  const int quad = lane >> 4;
  const int m0 = blockIdx.y * 64;
  const int n0 = blockIdx.x * 128;
  const int wm = (wid & 1) * 32;
  const int wn = (wid >> 1) * 64;
  const int srow = tid >> 2;
  const int schunk = tid & 3;

  const bf16* Ap = A + (size_t)(m0 + srow) * lda + schunk * 8;
  const bf16* Bp0 = Bw + (size_t)(n0 + srow) * K + schunk * 8;
  const bf16* Bp1 = Bp0 + (size_t)64 * K;
  bf16* AsW  = As + wid * 512;
  bf16* BsW0 = Bs + wid * 512;
  bf16* BsW1 = Bs + 2048 + wid * 512;

  v_f32x4 acc[2][4];
  #pragma unroll
  for (int i = 0; i < 2; i++)
    #pragma unroll
    for (int j = 0; j < 4; j++)
      #pragma unroll
      for (int r = 0; r < 4; r++) acc[i][j][r] = 0.0f;

  const int nk = K >> 5;
  for (int kt = 0; kt < nk; kt++) {
    gl_lds16(Ap + kt * 32, AsW);
    gl_lds16(Bp0 + kt * 32, BsW0);
    gl_lds16(Bp1 + kt * 32, BsW1);
    __syncthreads();
    v_bf16x8 af[2], bfw[4];
    #pragma unroll
    for (int i = 0; i < 2; i++)
      af[i] = *(const v_bf16x8*)&As[(wm + i * 16 + c) * 32 + quad * 8];
    #pragma unroll
    for (int j = 0; j < 4; j++)
      bfw[j] = *(const v_bf16x8*)&Bs[(wn + j * 16 + c) * 32 + quad * 8];
    #pragma unroll
    for (int i = 0; i < 2; i++)
      #pragma unroll
      for (int j = 0; j < 4; j++)
        acc[i][j] = __builtin_amdgcn_mfma_f32_16x16x32_bf16(af[i], bfw[j], acc[i][j], 0, 0, 0);
    __syncthreads();
  }

  #pragma unroll
  for (int i = 0; i < 2; i++)
    #pragma unroll
    for (int j = 0; j < 4; j++)
      #pragma unroll
      for (int r = 0; r < 4; r++) {
        int rg = m0 + wm + i * 16 + quad * 4 + r;
        int cg = n0 + wn + j * 16 + c;
        size_t idx = (size_t)rg * N + cg;
        float v = acc[i][j][r];
        if (RES) v += res[idx];
        if (OUTF32) ((float*)Cout)[idx] = v;
        else ((bf16*)Cout)[idx] = __float2bfloat16(v);
      }
}

// ---------------- V transpose: qkv V-part -> VtG[bh][d][t] ----------------
__global__ __launch_bounds__(256) void vtrans_kernel(const bf16* __restrict__ qkv,
                                                     bf16* __restrict__ VtG) {
  __shared__ alignas(16) bf16 Vs[64 * 72];
  const int tid = threadIdx.x;
  const int t0 = blockIdx.x * 64;
  const int bh = blockIdx.y;
  const int b = bh >> 4, h = bh & 15;
  const int srow = tid >> 2, schunk = tid & 3;
  {
    const bf16* src = qkv + (size_t)(b * NT + t0 + srow) * 3072 + 2048 + h * 64 + schunk * 16;
    *(v_u16x8*)&Vs[srow * 72 + schunk * 16] = *(const v_u16x8*)src;
    *(v_u16x8*)&Vs[srow * 72 + schunk * 16 + 8] = *(const v_u16x8*)(src + 8);
  }
  __syncthreads();
  const unsigned short* Vsu = (const unsigned short*)Vs;
  v_u16x8 a, bvec;
  #pragma unroll
  for (int i = 0; i < 8; i++) a[i] = Vsu[(schunk * 16 + i) * 72 + srow];
  #pragma unroll
  for (int i = 0; i < 8; i++) bvec[i] = Vsu[(schunk * 16 + 8 + i) * 72 + srow];
  bf16* dst = VtG + (size_t)(bh * 64 + srow) * NT + t0 + schunk * 16;
  *(v_u16x8*)dst = a;
  *(v_u16x8*)(dst + 8) = bvec;
}

// ---------------- Flash attention (causal), Q-tile 64, no-max softmax (r5 structure) ----------------
__global__ __launch_bounds__(256) void attn_kernel(const bf16* __restrict__ qkv,
                                                   const bf16* __restrict__ VtG,
                                                   bf16* __restrict__ out) {
  __shared__ alignas(16) bf16 Qs[64 * 72];
  __shared__ alignas(16) bf16 Ks[64 * 72];
  __shared__ alignas(16) bf16 Vt[64 * 72];
  __shared__ alignas(16) bf16 Ps[64 * 72];
  const int tid = threadIdx.x;
  const int w = tid >> 6;
  const int lane = tid & 63;
  const int c = lane & 15;
  const int quad = lane >> 4;
  // balance swizzle: resident sets {a, a+8, a+16, a+24} in j5 -> qt sums constant
  const int id = blockIdx.x;
  const int bh = id & 31;
  const int j5 = id >> 5;
  const int j0 = j5 & 7;
  const int qt = (j5 & 24) | (((j5 >> 3) & 1) ? (7 - j0) : j0);
  const int b = bh >> 4;
  const int h = bh & 15;
  const int srow = tid >> 2;
  const int schunk = tid & 3;

  {  // stage Q tile [64 q][64 d]
    const bf16* src = qkv + (size_t)(b * NT + qt * 64 + srow) * 3072 + h * 64 + schunk * 16;
    *(v_u16x8*)&Qs[srow * 72 + schunk * 16] = *(const v_u16x8*)src;
    *(v_u16x8*)&Qs[srow * 72 + schunk * 16 + 8] = *(const v_u16x8*)(src + 8);
  }
  __syncthreads();
  v_bf16x8 aq0 = *(const v_bf16x8*)&Qs[(w * 16 + c) * 72 + quad * 8];
  v_bf16x8 aq1 = *(const v_bf16x8*)&Qs[(w * 16 + c) * 72 + 32 + quad * 8];

  float l_part[4];
  v_f32x4 o[4];
  #pragma unroll
  for (int r = 0; r < 4; r++) l_part[r] = 0.0f;
  #pragma unroll
  for (int j = 0; j < 4; j++)
    #pragma unroll
    for (int r = 0; r < 4; r++) o[j][r] = 0.0f;

  for (int kt = 0; kt <= qt; kt++) {
    {  // stage K [64 k][64 d] and Vt [64 d][64 k] (pre-transposed in global)
      const bf16* ksrc = qkv + (size_t)(b * NT + kt * 64 + srow) * 3072 + 1024 + h * 64 + schunk * 16;
      *(v_u16x8*)&Ks[srow * 72 + schunk * 16] = *(const v_u16x8*)ksrc;
      *(v_u16x8*)&Ks[srow * 72 + schunk * 16 + 8] = *(const v_u16x8*)(ksrc + 8);
      const bf16* vsrc = VtG + (size_t)(bh * 64 + srow) * NT + kt * 64 + schunk * 16;
      *(v_u16x8*)&Vt[srow * 72 + schunk * 16] = *(const v_u16x8*)vsrc;
      *(v_u16x8*)&Vt[srow * 72 + schunk * 16 + 8] = *(const v_u16x8*)(vsrc + 8);
    }
    __syncthreads();

    const bool diag = (kt == qt);
    #pragma unroll
    for (int j = 0; j < 4; j++) {
      v_bf16x8 bk0 = *(const v_bf16x8*)&Ks[(j * 16 + c) * 72 + quad * 8];
      v_bf16x8 bk1 = *(const v_bf16x8*)&Ks[(j * 16 + c) * 72 + 32 + quad * 8];
      v_f32x4 z;
      #pragma unroll
      for (int r = 0; r < 4; r++) z[r] = 0.0f;
      z = __builtin_amdgcn_mfma_f32_16x16x32_bf16(aq0, bk0, z, 0, 0, 0);
      z = __builtin_amdgcn_mfma_f32_16x16x32_bf16(aq1, bk1, z, 0, 0, 0);
      #pragma unroll
      for (int r = 0; r < 4; r++) {
        float p = __expf(z[r] * 0.125f);
        if (diag && (j * 16 + c) > (w * 16 + quad * 4 + r)) p = 0.0f;
        l_part[r] += p;
        Ps[(w * 16 + quad * 4 + r) * 72 + j * 16 + c] = __float2bfloat16(p);
      }
    }
    #pragma unroll
    for (int ks = 0; ks < 2; ks++) {
      v_bf16x8 ap = *(const v_bf16x8*)&Ps[(w * 16 + c) * 72 + ks * 32 + quad * 8];
      #pragma unroll
      for (int jn = 0; jn < 4; jn++) {
        v_bf16x8 bv = *(const v_bf16x8*)&Vt[(jn * 16 + c) * 72 + ks * 32 + quad * 8];
        o[jn] = __builtin_amdgcn_mfma_f32_16x16x32_bf16(ap, bv, o[jn], 0, 0, 0);
      }
    }
    __syncthreads();
  }

  #pragma unroll
  for (int r = 0; r < 4; r++) {
    float l = l_part[r];
    l += __shfl_xor(l, 1, 64);
    l += __shfl_xor(l, 2, 64);
    l += __shfl_xor(l, 4, 64);
    l += __shfl_xor(l, 8, 64);
    l_part[r] = l;
  }

  #pragma unroll
  for (int jn = 0; jn < 4; jn++)
    #pragma unroll
    for (int r = 0; r < 4; r++) {
      int qg = qt * 64 + w * 16 + quad * 4 + r;
      out[(size_t)(b * NT + qg) * ND + h * 64 + jn * 16 + c] =
          __float2bfloat16(o[jn][r] / l_part[r]);
    }
}

// ---------------- fused: rmsnorm2 + zg proj (K=1024) + P2 proj (K=64) + scanprep ----------------
__global__ __launch_bounds__(256) void proj_scan_kernel(
    const float* __restrict__ x1, const float* __restrict__ n2w,
    const bf16* __restrict__ W1, const bf16* __restrict__ W2,
    const float* __restrict__ dt_b,
    float* __restrict__ dt_a, float* __restrict__ dtz_a,
    float* __restrict__ gate_a, float* __restrict__ P2) {
  __shared__ alignas(16) bf16 h2S[16 * 1032];
  __shared__ alignas(16) bf16 Bs[128 * 32];
  __shared__ alignas(16) bf16 zgS[16 * 136];
  const int tid = threadIdx.x;
  const int w = tid >> 6, lane = tid & 63, c = lane & 15, quad = lane >> 4;
  const int m0 = blockIdx.x * 16;
  unsigned short* h2Su = (unsigned short*)h2S;
  unsigned short* zgSu = (unsigned short*)zgS;

  // A) rmsnorm2: rows m0..m0+15 of x1 -> h2S (bf16)
  {
    const int r16 = tid >> 4, ct = tid & 15;
    const float* xr = x1 + (size_t)(m0 + r16) * ND + ct * 64;
    v_f32x4 xv[16];
    float ss = 0.0f;
    #pragma unroll
    for (int i = 0; i < 16; i++) {
      xv[i] = *(const v_f32x4*)(xr + i * 4);
      ss += xv[i][0]*xv[i][0] + xv[i][1]*xv[i][1] + xv[i][2]*xv[i][2] + xv[i][3]*xv[i][3];
    }
    ss += __shfl_xor(ss, 1, 64);
    ss += __shfl_xor(ss, 2, 64);
    ss += __shfl_xor(ss, 4, 64);
    ss += __shfl_xor(ss, 8, 64);
    float sc = rsqrtf(ss * (1.0f / ND) + RMS_EPS);
    const float* wr = n2w + ct * 64;
    #pragma unroll
    for (int i = 0; i < 16; i++) {
      v_f32x4 wv = *(const v_f32x4*)(wr + i * 4);
      v_u16x4 o;
      o[0] = f2b(xv[i][0] * sc * wv[0]);
      o[1] = f2b(xv[i][1] * sc * wv[1]);
      o[2] = f2b(xv[i][2] * sc * wv[2]);
      o[3] = f2b(xv[i][3] * sc * wv[3]);
      *(v_u16x4*)&h2Su[r16 * 1032 + ct * 64 + i * 4] = o;
    }
  }
  __syncthreads();

  const int lrow = lane >> 2, lk = lane & 3;
  // B) zg[16 x 128] = h2 @ W1^T, K=1024
  v_f32x4 acc[2];
  #pragma unroll
  for (int j = 0; j < 2; j++)
    #pragma unroll
    for (int r = 0; r < 4; r++) acc[j][r] = 0.0f;
  for (int kt = 0; kt < 32; kt++) {
    gl_lds16(W1 + (size_t)(w * 32 + lrow) * 1024 + kt * 32 + lk * 8, Bs + (w * 32) * 32);
    gl_lds16(W1 + (size_t)(w * 32 + 16 + lrow) * 1024 + kt * 32 + lk * 8, Bs + (w * 32 + 16) * 32);
    __syncthreads();
    v_bf16x8 af = *(const v_bf16x8*)&h2S[c * 1032 + kt * 32 + quad * 8];
    #pragma unroll
    for (int j = 0; j < 2; j++) {
      v_bf16x8 bfw = *(const v_bf16x8*)&Bs[(w * 32 + j * 16 + c) * 32 + quad * 8];
      acc[j] = __builtin_amdgcn_mfma_f32_16x16x32_bf16(af, bfw, acc[j], 0, 0, 0);
    }
    __syncthreads();
  }
  // C) write zg tile to LDS (C-layout rows quad*4+r, cols w*32+j*16+c)
  #pragma unroll
  for (int j = 0; j < 2; j++)
    #pragma unroll
    for (int r = 0; r < 4; r++)
      zgSu[(quad * 4 + r) * 136 + w * 32 + j * 16 + c] = f2b(acc[j][r]);
  __syncthreads();

  // D) P2[16 x 128] = zg[:, 0:64] @ W2^T, K=64
  v_f32x4 acc2[2];
  #pragma unroll
  for (int j = 0; j < 2; j++)
    #pragma unroll
    for (int r = 0; r < 4; r++) acc2[j][r] = 0.0f;
  for (int kt = 0; kt < 2; kt++) {
    gl_lds16(W2 + (size_t)(w * 32 + lrow) * 64 + kt * 32 + lk * 8, Bs + (w * 32) * 32);
    gl_lds16(W2 + (size_t)(w * 32 + 16 + lrow) * 64 + kt * 32 + lk * 8, Bs + (w * 32 + 16) * 32);
    __syncthreads();
    v_bf16x8 af = *(const v_bf16x8*)&zgS[c * 136 + kt * 32 + quad * 8];
    #pragma unroll
    for (int j = 0; j < 2; j++) {
      v_bf16x8 bfw = *(const v_bf16x8*)&Bs[(w * 32 + j * 16 + c) * 32 + quad * 8];
      acc2[j] = __builtin_amdgcn_mfma_f32_16x16x32_bf16(af, bfw, acc2[j], 0, 0, 0);
    }
    __syncthreads();
  }

  // E) epilogue: softplus/dtz (cols<64) | P2 store + silu gate (cols>=64)
  #pragma unroll
  for (int j = 0; j < 2; j++)
    #pragma unroll
    for (int r = 0; r < 4; r++) {
      const int row = quad * 4 + r;
      const int col = w * 32 + j * 16 + c;
      const size_t grow = (size_t)(m0 + row);
      if (w < 2) {  // col in [0,64)
        float z = b2f(zgSu[row * 136 + col]);
        float a = acc2[j][r] + dt_b[col];
        float dt = (a > 20.0f) ? a : log1pf(__expf(a));
        dt_a[grow * NSC + col] = dt;
        dtz_a[grow * NSC + col] = dt * z;
      } else {      // col in [64,128)
        P2[grow * 128 + col] = acc2[j][r];
        float g = b2f(zgSu[row * 136 + col]);
        gate_a[grow * NSC + (col - 64)] = g / (1.0f + __expf(-g));
      }
    }
}

// ---------------- chunked parallel scan ----------------
__global__ __launch_bounds__(256) void scanA_kernel(
    const float* __restrict__ dt_a, const float* __restrict__ dtz_a,
    const float* __restrict__ P2, const float* __restrict__ A_log,
    float* __restrict__ Pbuf, float* __restrict__ Sbuf) {
  __shared__ float dtS[CLEN * 16], dtzS[CLEN * 16], biS[CLEN * 16];
  const int k = blockIdx.x, scg = blockIdx.y, b = blockIdx.z;
  const int tid = threadIdx.x;
  const int t0 = k * CLEN;
  {
    int r = tid >> 2, c4 = (tid & 3) * 4;
    *(v_f32x4*)&dtS[r * 16 + c4]  = *(const v_f32x4*)&dt_a[(size_t)(b * NT + t0 + r) * NSC + scg * 16 + c4];
    *(v_f32x4*)&dtzS[r * 16 + c4] = *(const v_f32x4*)&dtz_a[(size_t)(b * NT + t0 + r) * NSC + scg * 16 + c4];
    *(v_f32x4*)&biS[r * 16 + c4]  = *(const v_f32x4*)&P2[(size_t)(b * NT + t0 + r) * 128 + 64 + c4];
  }
  __syncthreads();
  const int st = tid & 15, scl = tid >> 4;
  const float A = -__expf(A_log[(scg * 16 + scl) * NST + st]);
  float P = 1.0f, s = 0.0f;
  #pragma unroll
  for (int t = 0; t < CLEN; t++) {
    float a = fmaf(dtS[t * 16 + scl], A, 1.0f);
    float u = dtzS[t * 16 + scl] * biS[t * 16 + st];
    P *= a;
    s = fmaf(a, s, u);
  }
  size_t idx = (size_t)(b * NCHUNK + k) * 1024 + scg * 256 + tid;
  Pbuf[idx] = P;
  Sbuf[idx] = s;
}

// scanC with scanB folded in: each block redoes the <=31-step prefix combine
__global__ __launch_bounds__(256) void scanC_kernel(
    const float* __restrict__ dt_a, const float* __restrict__ dtz_a,
    const float* __restrict__ P2, const float* __restrict__ gate_a,
    const float* __restrict__ A_log, const float* __restrict__ Pbuf,
    const float* __restrict__ Sbuf, bf16* __restrict__ ys) {
  __shared__ float dtS[CLEN * 16], dtzS[CLEN * 16], biS[CLEN * 16], ciS[CLEN * 16], gS[CLEN * 16];
  const int k = blockIdx.x, scg = blockIdx.y, b = blockIdx.z;
  const int tid = threadIdx.x;
  const int t0 = k * CLEN;
  {
    int r = tid >> 2, c4 = (tid & 3) * 4;
    *(v_f32x4*)&dtS[r * 16 + c4]  = *(const v_f32x4*)&dt_a[(size_t)(b * NT + t0 + r) * NSC + scg * 16 + c4];
    *(v_f32x4*)&dtzS[r * 16 + c4] = *(const v_f32x4*)&dtz_a[(size_t)(b * NT + t0 + r) * NSC + scg * 16 + c4];
    *(v_f32x4*)&biS[r * 16 + c4]  = *(const v_f32x4*)&P2[(size_t)(b * NT + t0 + r) * 128 + 64 + c4];
    *(v_f32x4*)&ciS[r * 16 + c4]  = *(const v_f32x4*)&P2[(size_t)(b * NT + t0 + r) * 128 + 80 + c4];
    *(v_f32x4*)&gS[r * 16 + c4]   = *(const v_f32x4*)&gate_a[(size_t)(b * NT + t0 + r) * NSC + scg * 16 + c4];
  }
  const int st = tid & 15, scl = tid >> 4;
  const float A = -__expf(A_log[(scg * 16 + scl) * NST + st]);
  // prefix combine over earlier chunks (scanB folded)
  float s = 0.0f;
  for (int kk = 0; kk < k; kk++) {
    size_t idx = (size_t)(b * NCHUNK + kk) * 1024 + scg * 256 + tid;
    s = fmaf(Pbuf[idx], s, Sbuf[idx]);
  }
  __syncthreads();
  for (int t = 0; t < CLEN; t++) {
    float a = fmaf(dtS[t * 16 + scl], A, 1.0f);
    float u = dtzS[t * 16 + scl] * biS[t * 16 + st];
    s = fmaf(a, s, u);
    float pv = s * ciS[t * 16 + st];
    pv += __shfl_xor(pv, 1, 64);
    pv += __shfl_xor(pv, 2, 64);
    pv += __shfl_xor(pv, 4, 64);
    pv += __shfl_xor(pv, 8, 64);
    if (st == 0)
      ys[(size_t)(b * NT + t0 + t) * NSC + scg * 16 + scl] = __float2bfloat16(pv * gS[t * 16 + scl]);
  }
}

extern "C" void kernel_launch(void* const* d_in, const int* in_sizes, int n_in,
                              void* d_out, int out_size, void* d_ws, size_t ws_size,
                              hipStream_t stream) {
  const float* x      = (const float*)d_in[0];
  const float* qkv_w  = (const float*)d_in[1];
  const float* o_w    = (const float*)d_in[2];
  const float* n1w    = (const float*)d_in[3];
  const float* n2w    = (const float*)d_in[4];
  const float* in_w   = (const float*)d_in[5];
  const float* out_w  = (const float*)d_in[6];
  const float* A_log  = (const float*)d_in[7];
  const float* Bp_w   = (const float*)d_in[8];
  const float* Cp_w   = (const float*)d_in[9];
  const float* dt_w   = (const float*)d_in[10];
  const float* dt_b   = (const float*)d_in[11];
  const float* gate_w = (const float*)d_in[12];
  float* out = (float*)d_out;

  char* ws = (char*)d_ws;
  size_t off = 0;
  auto alloc = [&](size_t bytes) {
    char* p = ws + off;
    off += (bytes + 255) & ~(size_t)255;
    return p;
  };
  bf16* qkvw_b = (bf16*)alloc((size_t)3 * ND * ND * 2);
  bf16* ow_b   = (bf16*)alloc((size_t)ND * ND * 2);
  bf16* outw_b = (bf16*)alloc((size_t)ND * NSC * 2);
  bf16* W1     = (bf16*)alloc((size_t)128 * ND * 2);
  bf16* W2     = (bf16*)alloc((size_t)128 * NSC * 2);
  char* region0 = alloc((size_t)NM * 3 * ND * 2);         // qkv bf16 -> x1 f32
  char* region1 = alloc((size_t)NM * ND * 2);             // h -> attnout
  bf16* VtG    = (bf16*)alloc((size_t)NB * NH * 64 * NT * 2);
  float* P2    = (float*)alloc((size_t)NM * 128 * 4);
  float* dt_a  = (float*)alloc((size_t)NM * NSC * 4);
  float* dtz_a = (float*)alloc((size_t)NM * NSC * 4);
  float* gate_a= (float*)alloc((size_t)NM * NSC * 4);
  bf16*  ys    = (bf16*)alloc((size_t)NM * NSC * 2);
  float* Pbuf  = (float*)alloc((size_t)NB * NCHUNK * 1024 * 4);
  float* Sbuf  = (float*)alloc((size_t)NB * NCHUNK * 1024 * 4);

  bf16*  qkv     = (bf16*)region0;
  float* x1      = (float*)region0;   // aliases qkv (dead after attn)
  bf16*  h       = (bf16*)region1;
  bf16*  attnout = (bf16*)region1;    // aliases h (dead after qkv gemm)

  cvt_rms_kernel<<<4295 + NM, 256, 0, stream>>>(qkv_w, o_w, out_w, in_w, gate_w, dt_w,
                                                Bp_w, Cp_w, qkvw_b, ow_b, outw_b, W1, W2,
                                                x, n1w, h);
  gemm_bt_kernel<false, false><<<dim3(3 * ND / 128, NM / 128), 256, 0, stream>>>(
      h, qkvw_b, nullptr, (void*)qkv, 3 * ND, ND, ND);
  vtrans_kernel<<<dim3(NT / 64, NB * NH), 256, 0, stream>>>(qkv, VtG);
  attn_kernel<<<(NT / 64) * NB * NH, 256, 0, stream>>>(qkv, VtG, attnout);
  gemm_bt64_kernel<true, true><<<dim3(ND / 128, NM / 64), 256, 0, stream>>>(
      attnout, ow_b, x, (void*)x1, ND, ND, ND);
  proj_scan_kernel<<<NM / 16, 256, 0, stream>>>(x1, n2w, W1, W2, dt_b,
                                                dt_a, dtz_a, gate_a, P2);
  scanA_kernel<<<dim3(NCHUNK, 4, NB), 256, 0, stream>>>(dt_a, dtz_a, P2, A_log, Pbuf, Sbuf);
  scanC_kernel<<<dim3(NCHUNK, 4, NB), 256, 0, stream>>>(dt_a, dtz_a, P2, gate_a, A_log,
                                                        Pbuf, Sbuf, ys);
  gemm_bt64_kernel<true, true><<<dim3(ND / 128, NM / 64), 256, 0, stream>>>(
      ys, outw_b, x1, (void*)out, ND, NSC, NSC);
}

// Round 8
// 269.797 us; speedup vs baseline: 1.1129x; 1.0030x over previous
//
#include <hip/hip_runtime.h>
#include <hip/hip_bf16.h>
#include <math.h>

typedef __hip_bfloat16 bf16;
typedef __attribute__((ext_vector_type(4))) float v_f32x4;
typedef __attribute__((ext_vector_type(4))) unsigned short v_u16x4;
typedef __attribute__((ext_vector_type(8))) unsigned short v_u16x8;
typedef __attribute__((ext_vector_type(8))) __bf16 v_bf16x8;
typedef __attribute__((ext_vector_type(4))) __bf16 v_bf16x4;
typedef __attribute__((ext_vector_type(4))) short v_s16x4;

#define NB 2
#define NT 2048
#define ND 1024
#define NH 16
#define NSC 64
#define NST 16
#define NM (NB*NT)
#define RMS_EPS 1.1920929e-07f
#define NCHUNK 32
#define CLEN 64

__device__ inline float b2f(unsigned short u) {
  union { unsigned int i; float f; } v; v.i = ((unsigned int)u) << 16; return v.f;
}
__device__ inline unsigned short f2b(float f) {  // RNE f32->bf16
  union { float f; unsigned int i; } v; v.f = f;
  unsigned int r = (v.i + 0x7FFF + ((v.i >> 16) & 1)) >> 16;
  return (unsigned short)r;
}

// K=16 bf16 MFMA with builtin-name fallback
__device__ inline v_f32x4 mfma16(v_bf16x4 a, v_bf16x4 b, v_f32x4 c) {
#if __has_builtin(__builtin_amdgcn_mfma_f32_16x16x16_bf16)
  return __builtin_amdgcn_mfma_f32_16x16x16_bf16(a, b, c, 0, 0, 0);
#else
  union U { v_bf16x4 h; v_s16x4 s; };
  U ua, ub; ua.h = a; ub.h = b;
  return __builtin_amdgcn_mfma_f32_16x16x16bf16_1k(ua.s, ub.s, c, 0, 0, 0);
#endif
}

// async global->LDS, 16B per lane; LDS dest = wave-uniform base + lane*16
__device__ inline void gl_lds16(const bf16* g, bf16* l) {
  __builtin_amdgcn_global_load_lds((__attribute__((address_space(1))) void*)g,
                                   (__attribute__((address_space(3))) void*)l,
                                   16, 0, 0);
}

// ---------------- fused: all weight cvt (blocks 0..4294) + rmsnorm1 (blocks 4295..8390) ----------------
__global__ __launch_bounds__(256) void cvt_rms_kernel(
    const float* __restrict__ qkv_w, const float* __restrict__ o_w,
    const float* __restrict__ out_w, const float* __restrict__ in_w,
    const float* __restrict__ gate_w, const float* __restrict__ dt_w,
    const float* __restrict__ Bp_w, const float* __restrict__ Cp_w,
    bf16* __restrict__ qkvw_b, bf16* __restrict__ ow_b, bf16* __restrict__ outw_b,
    bf16* __restrict__ W1, bf16* __restrict__ W2,
    const float* __restrict__ x, const float* __restrict__ n1w, bf16* __restrict__ h) {
  const int blk = blockIdx.x, t = threadIdx.x;
  if (blk >= 4295) {  // rmsnorm1 of x row -> h
    const int row = blk - 4295;
    v_f32x4 xv = *(const v_f32x4*)(x + (size_t)row * ND + t * 4);
    float s = xv[0]*xv[0] + xv[1]*xv[1] + xv[2]*xv[2] + xv[3]*xv[3];
    #pragma unroll
    for (int off = 32; off; off >>= 1) s += __shfl_xor(s, off, 64);
    __shared__ float red[4];
    __shared__ float scale_s;
    if ((t & 63) == 0) red[t >> 6] = s;
    __syncthreads();
    if (t == 0) scale_s = rsqrtf((red[0] + red[1] + red[2] + red[3]) * (1.0f / ND) + RMS_EPS);
    __syncthreads();
    float sc = scale_s;
    v_f32x4 wv = *(const v_f32x4*)(n1w + t * 4);
    v_u16x4 o;
    o[0] = f2b(xv[0] * sc * wv[0]);
    o[1] = f2b(xv[1] * sc * wv[1]);
    o[2] = f2b(xv[2] * sc * wv[2]);
    o[3] = f2b(xv[3] * sc * wv[3]);
    *(v_u16x4*)((unsigned short*)h + (size_t)row * ND + t * 4) = o;
    return;
  }
  const float* src; bf16* dst; int base;
  if (blk < 3072)      { src = qkv_w;  dst = qkvw_b;      base = blk; }
  else if (blk < 4096) { src = o_w;    dst = ow_b;        base = blk - 3072; }
  else if (blk < 4160) { src = out_w;  dst = outw_b;      base = blk - 4096; }
  else if (blk < 4224) { src = in_w;   dst = W1;          base = blk - 4160; }
  else if (blk < 4288) { src = gate_w; dst = W1 + 65536;  base = blk - 4224; }
  else if (blk < 4292) { src = dt_w;   dst = W2;          base = blk - 4288; }
  else if (blk == 4292){ src = Bp_w;   dst = W2 + 4096;   base = 0; }
  else if (blk == 4293){ src = Cp_w;   dst = W2 + 5120;   base = 0; }
  else {  // zero tail of W2 (rows 96..127)
    v_u16x8 z;
    #pragma unroll
    for (int i = 0; i < 8; i++) z[i] = 0;
    *(v_u16x8*)(W2 + 6144 + t * 8) = z;
    return;
  }
  int i = base * 256 + t;
  v_f32x4 v = ((const v_f32x4*)src)[i];
  v_u16x4 o;
  o[0] = f2b(v[0]); o[1] = f2b(v[1]); o[2] = f2b(v[2]); o[3] = f2b(v[3]);
  ((v_u16x4*)dst)[i] = o;
}

// ---------------- GEMM 128x128: C[M,N] = A[M,K(lda)] @ Bw[N,K]^T ----------------
template <bool RES, bool OUTF32>
__global__ __launch_bounds__(256) void gemm_bt_kernel(
    const bf16* __restrict__ A, const bf16* __restrict__ Bw,
    const float* __restrict__ res, void* __restrict__ Cout, int N, int K, int lda) {
  __shared__ alignas(16) bf16 As[128 * 32];
  __shared__ alignas(16) bf16 Bs[128 * 32];
  const int tid = threadIdx.x;
  const int wid = tid >> 6;
  const int lane = tid & 63;
  const int c = lane & 15;
  const int quad = lane >> 4;
  const int m0 = blockIdx.y * 128;
  const int n0 = blockIdx.x * 128;
  const int wm = (wid >> 1) * 64;
  const int wn = (wid & 1) * 64;
  const int srow = tid >> 2;
  const int schunk = tid & 3;

  const bf16* Ap0 = A + (size_t)(m0 + srow) * lda + schunk * 8;
  const bf16* Ap1 = Ap0 + (size_t)64 * lda;
  const bf16* Bp0 = Bw + (size_t)(n0 + srow) * K + schunk * 8;
  const bf16* Bp1 = Bp0 + (size_t)64 * K;
  bf16* AsW0 = As + wid * 512;
  bf16* AsW1 = As + 2048 + wid * 512;
  bf16* BsW0 = Bs + wid * 512;
  bf16* BsW1 = Bs + 2048 + wid * 512;

  v_f32x4 acc[4][4];
  #pragma unroll
  for (int i = 0; i < 4; i++)
    #pragma unroll
    for (int j = 0; j < 4; j++)
      #pragma unroll
      for (int r = 0; r < 4; r++) acc[i][j][r] = 0.0f;

  const int nk = K >> 5;
  for (int kt = 0; kt < nk; kt++) {
    gl_lds16(Ap0 + kt * 32, AsW0);
    gl_lds16(Ap1 + kt * 32, AsW1);
    gl_lds16(Bp0 + kt * 32, BsW0);
    gl_lds16(Bp1 + kt * 32, BsW1);
    __syncthreads();
    v_bf16x8 af[4], bfw[4];
    #pragma unroll
    for (int i = 0; i < 4; i++)
      af[i] = *(const v_bf16x8*)&As[(wm + i * 16 + c) * 32 + quad * 8];
    #pragma unroll
    for (int j = 0; j < 4; j++)
      bfw[j] = *(const v_bf16x8*)&Bs[(wn + j * 16 + c) * 32 + quad * 8];
    #pragma unroll
    for (int i = 0; i < 4; i++)
      #pragma unroll
      for (int j = 0; j < 4; j++)
        acc[i][j] = __builtin_amdgcn_mfma_f32_16x16x32_bf16(af[i], bfw[j], acc[i][j], 0, 0, 0);
    __syncthreads();
  }

  #pragma unroll
  for (int i = 0; i < 4; i++)
    #pragma unroll
    for (int j = 0; j < 4; j++)
      #pragma unroll
      for (int r = 0; r < 4; r++) {
        int rg = m0 + wm + i * 16 + quad * 4 + r;
        int cg = n0 + wn + j * 16 + c;
        size_t idx = (size_t)rg * N + cg;
        float v = acc[i][j][r];
        if (RES) v += res[idx];
        if (OUTF32) ((float*)Cout)[idx] = v;
        else ((bf16*)Cout)[idx] = __float2bfloat16(v);
      }
}

// ---------------- GEMM 64x128 ----------------
template <bool RES, bool OUTF32>
__global__ __launch_bounds__(256) void gemm_bt64_kernel(
    const bf16* __restrict__ A, const bf16* __restrict__ Bw,
    const float* __restrict__ res, void* __restrict__ Cout, int N, int K, int lda) {
  __shared__ alignas(16) bf16 As[64 * 32];
  __shared__ alignas(16) bf16 Bs[128 * 32];
  const int tid = threadIdx.x;
  const int wid = tid >> 6;
  const int lane = tid & 63;
  const int c = lane & 15;
  const int quad = lane >> 4;
  const int m0 = blockIdx.y * 64;
  const int n0 = blockIdx.x * 128;
  const int wm = (wid & 1) * 32;
  const int wn = (wid >> 1) * 64;
  const int srow = tid >> 2;
  const int schunk = tid & 3;

  const bf16* Ap = A + (size_t)(m0 + srow) * lda + schunk * 8;
  const bf16* Bp0 = Bw + (size_t)(n0 + srow) * K + schunk * 8;
  const bf16* Bp1 = Bp0 + (size_t)64 * K;
  bf16* AsW  = As + wid * 512;
  bf16* BsW0 = Bs + wid * 512;
  bf16* BsW1 = Bs + 2048 + wid * 512;

  v_f32x4 acc[2][4];
  #pragma unroll
  for (int i = 0; i < 2; i++)
    #pragma unroll
    for (int j = 0; j < 4; j++)
      #pragma unroll
      for (int r = 0; r < 4; r++) acc[i][j][r] = 0.0f;

  const int nk = K >> 5;
  for (int kt = 0; kt < nk; kt++) {
    gl_lds16(Ap + kt * 32, AsW);
    gl_lds16(Bp0 + kt * 32, BsW0);
    gl_lds16(Bp1 + kt * 32, BsW1);
    __syncthreads();
    v_bf16x8 af[2], bfw[4];
    #pragma unroll
    for (int i = 0; i < 2; i++)
      af[i] = *(const v_bf16x8*)&As[(wm + i * 16 + c) * 32 + quad * 8];
    #pragma unroll
    for (int j = 0; j < 4; j++)
      bfw[j] = *(const v_bf16x8*)&Bs[(wn + j * 16 + c) * 32 + quad * 8];
    #pragma unroll
    for (int i = 0; i < 2; i++)
      #pragma unroll
      for (int j = 0; j < 4; j++)
        acc[i][j] = __builtin_amdgcn_mfma_f32_16x16x32_bf16(af[i], bfw[j], acc[i][j], 0, 0, 0);
    __syncthreads();
  }

  #pragma unroll
  for (int i = 0; i < 2; i++)
    #pragma unroll
    for (int j = 0; j < 4; j++)
      #pragma unroll
      for (int r = 0; r < 4; r++) {
        int rg = m0 + wm + i * 16 + quad * 4 + r;
        int cg = n0 + wn + j * 16 + c;
        size_t idx = (size_t)rg * N + cg;
        float v = acc[i][j][r];
        if (RES) v += res[idx];
        if (OUTF32) ((float*)Cout)[idx] = v;
        else ((bf16*)Cout)[idx] = __float2bfloat16(v);
      }
}

// ---------------- V transpose: qkv V-part -> VtG[bh][d][t] ----------------
__global__ __launch_bounds__(256) void vtrans_kernel(const bf16* __restrict__ qkv,
                                                     bf16* __restrict__ VtG) {
  __shared__ alignas(16) bf16 Vs[64 * 72];
  const int tid = threadIdx.x;
  const int t0 = blockIdx.x * 64;
  const int bh = blockIdx.y;
  const int b = bh >> 4, h = bh & 15;
  const int srow = tid >> 2, schunk = tid & 3;
  {
    const bf16* src = qkv + (size_t)(b * NT + t0 + srow) * 3072 + 2048 + h * 64 + schunk * 16;
    *(v_u16x8*)&Vs[srow * 72 + schunk * 16] = *(const v_u16x8*)src;
    *(v_u16x8*)&Vs[srow * 72 + schunk * 16 + 8] = *(const v_u16x8*)(src + 8);
  }
  __syncthreads();
  const unsigned short* Vsu = (const unsigned short*)Vs;
  v_u16x8 a, bvec;
  #pragma unroll
  for (int i = 0; i < 8; i++) a[i] = Vsu[(schunk * 16 + i) * 72 + srow];
  #pragma unroll
  for (int i = 0; i < 8; i++) bvec[i] = Vsu[(schunk * 16 + 8 + i) * 72 + srow];
  bf16* dst = VtG + (size_t)(bh * 64 + srow) * NT + t0 + schunk * 16;
  *(v_u16x8*)dst = a;
  *(v_u16x8*)(dst + 8) = bvec;
}

// ---------------- Flash attention (causal), S^T formulation, register-resident P ----------------
// QK^T computed as S^T = MFMA(A=K, B=Q)  -> C-layout leaves P in exactly the
// B-operand layout of mfma_16x16x16, so PV needs NO LDS round-trip for P.
__global__ __launch_bounds__(256) void attn_kernel(const bf16* __restrict__ qkv,
                                                   const bf16* __restrict__ VtG,
                                                   bf16* __restrict__ out) {
  __shared__ alignas(16) bf16 Qs[64 * 72];
  __shared__ alignas(16) bf16 Ks[64 * 72];
  __shared__ alignas(16) bf16 Vt[64 * 72];
  const int tid = threadIdx.x;
  const int w = tid >> 6;
  const int lane = tid & 63;
  const int c = lane & 15;
  const int quad = lane >> 4;
  const int id = blockIdx.x;
  const int bh = id & 31;
  const int j5 = id >> 5;
  const int j0 = j5 & 7;
  const int qt = (j5 & 24) | (((j5 >> 3) & 1) ? (7 - j0) : j0);
  const int b = bh >> 4;
  const int h = bh & 15;
  const int srow = tid >> 2;
  const int schunk = tid & 3;

  {  // stage Q tile [64 q][64 d]
    const bf16* src = qkv + (size_t)(b * NT + qt * 64 + srow) * 3072 + h * 64 + schunk * 16;
    *(v_u16x8*)&Qs[srow * 72 + schunk * 16] = *(const v_u16x8*)src;
    *(v_u16x8*)&Qs[srow * 72 + schunk * 16 + 8] = *(const v_u16x8*)(src + 8);
  }
  __syncthreads();
  // B-operand of QK (Q): lane holds Q[query=w*16+c][d=quad*8..]
  v_bf16x8 aq0 = *(const v_bf16x8*)&Qs[(w * 16 + c) * 72 + quad * 8];
  v_bf16x8 aq1 = *(const v_bf16x8*)&Qs[(w * 16 + c) * 72 + 32 + quad * 8];

  float l_part = 0.0f;
  v_f32x4 o[4];   // o[jd][r] = O[q = w*16+c][d = jd*16 + quad*4 + r]
  #pragma unroll
  for (int jd = 0; jd < 4; jd++)
    #pragma unroll
    for (int r = 0; r < 4; r++) o[jd][r] = 0.0f;

  const int qrow = w * 16 + c;  // query index within tile

  for (int kt = 0; kt <= qt; kt++) {
    {  // stage K [64 k][64 d] and Vt [64 d][64 k]
      const bf16* ksrc = qkv + (size_t)(b * NT + kt * 64 + srow) * 3072 + 1024 + h * 64 + schunk * 16;
      *(v_u16x8*)&Ks[srow * 72 + schunk * 16] = *(const v_u16x8*)ksrc;
      *(v_u16x8*)&Ks[srow * 72 + schunk * 16 + 8] = *(const v_u16x8*)(ksrc + 8);
      const bf16* vsrc = VtG + (size_t)(bh * 64 + srow) * NT + kt * 64 + schunk * 16;
      *(v_u16x8*)&Vt[srow * 72 + schunk * 16] = *(const v_u16x8*)vsrc;
      *(v_u16x8*)&Vt[srow * 72 + schunk * 16 + 8] = *(const v_u16x8*)(vsrc + 8);
    }
    __syncthreads();

    const bool diag = (kt == qt);
    v_bf16x4 pf[4];  // P fragments: pf[j][i] = P[q=w*16+c][key = j*16 + quad*4 + i]
    #pragma unroll
    for (int j = 0; j < 4; j++) {
      // S^T tile: A = K rows (j*16+c), B = Q
      v_bf16x8 ak0 = *(const v_bf16x8*)&Ks[(j * 16 + c) * 72 + quad * 8];
      v_bf16x8 ak1 = *(const v_bf16x8*)&Ks[(j * 16 + c) * 72 + 32 + quad * 8];
      v_f32x4 z;
      #pragma unroll
      for (int r = 0; r < 4; r++) z[r] = 0.0f;
      z = __builtin_amdgcn_mfma_f32_16x16x32_bf16(ak0, aq0, z, 0, 0, 0);
      z = __builtin_amdgcn_mfma_f32_16x16x32_bf16(ak1, aq1, z, 0, 0, 0);
      v_u16x4 pu;
      #pragma unroll
      for (int r = 0; r < 4; r++) {
        float p = __expf(z[r] * 0.125f);
        if (diag && (j * 16 + quad * 4 + r) > qrow) p = 0.0f;
        l_part += p;
        pu[r] = f2b(p);
      }
      union { v_u16x4 u; v_bf16x4 h; } cv; cv.u = pu;
      pf[j] = cv.h;
    }
    // O^T accumulation: D[m=d_local][n=q] += Vt-frag * P-frag  (K=16, P from regs)
    #pragma unroll
    for (int jd = 0; jd < 4; jd++)
      #pragma unroll
      for (int j = 0; j < 4; j++) {
        v_bf16x4 av = *(const v_bf16x4*)&Vt[(jd * 16 + c) * 72 + j * 16 + quad * 4];
        o[jd] = mfma16(av, pf[j], o[jd]);
      }
    __syncthreads();
  }

  // l: sum over the 4 quads holding this query's keys
  float l = l_part;
  l += __shfl_xor(l, 16, 64);
  l += __shfl_xor(l, 32, 64);
  const float inv = 1.0f / l;

  const int qg = qt * 64 + w * 16 + c;
  #pragma unroll
  for (int jd = 0; jd < 4; jd++) {
    v_u16x4 ov;
    #pragma unroll
    for (int r = 0; r < 4; r++) ov[r] = f2b(o[jd][r] * inv);
    *(v_u16x4*)((unsigned short*)out + (size_t)(b * NT + qg) * ND + h * 64 + jd * 16 + quad * 4) = ov;
  }
}

// ---------------- fused: rmsnorm2 + zg proj (K=1024) + P2 proj (K=64) + scanprep ----------------
__global__ __launch_bounds__(256) void proj_scan_kernel(
    const float* __restrict__ x1, const float* __restrict__ n2w,
    const bf16* __restrict__ W1, const bf16* __restrict__ W2,
    const float* __restrict__ dt_b,
    float* __restrict__ dt_a, float* __restrict__ dtz_a,
    float* __restrict__ gate_a, float* __restrict__ P2) {
  __shared__ alignas(16) bf16 h2S[16 * 1032];
  __shared__ alignas(16) bf16 Bs[128 * 32];
  __shared__ alignas(16) bf16 zgS[16 * 136];
  const int tid = threadIdx.x;
  const int w = tid >> 6, lane = tid & 63, c = lane & 15, quad = lane >> 4;
  const int m0 = blockIdx.x * 16;
  unsigned short* h2Su = (unsigned short*)h2S;
  unsigned short* zgSu = (unsigned short*)zgS;

  // A) rmsnorm2: rows m0..m0+15 of x1 -> h2S (bf16)
  {
    const int r16 = tid >> 4, ct = tid & 15;
    const float* xr = x1 + (size_t)(m0 + r16) * ND + ct * 64;
    v_f32x4 xv[16];
    float ss = 0.0f;
    #pragma unroll
    for (int i = 0; i < 16; i++) {
      xv[i] = *(const v_f32x4*)(xr + i * 4);
      ss += xv[i][0]*xv[i][0] + xv[i][1]*xv[i][1] + xv[i][2]*xv[i][2] + xv[i][3]*xv[i][3];
    }
    ss += __shfl_xor(ss, 1, 64);
    ss += __shfl_xor(ss, 2, 64);
    ss += __shfl_xor(ss, 4, 64);
    ss += __shfl_xor(ss, 8, 64);
    float sc = rsqrtf(ss * (1.0f / ND) + RMS_EPS);
    const float* wr = n2w + ct * 64;
    #pragma unroll
    for (int i = 0; i < 16; i++) {
      v_f32x4 wv = *(const v_f32x4*)(wr + i * 4);
      v_u16x4 o;
      o[0] = f2b(xv[i][0] * sc * wv[0]);
      o[1] = f2b(xv[i][1] * sc * wv[1]);
      o[2] = f2b(xv[i][2] * sc * wv[2]);
      o[3] = f2b(xv[i][3] * sc * wv[3]);
      *(v_u16x4*)&h2Su[r16 * 1032 + ct * 64 + i * 4] = o;
    }
  }
  __syncthreads();

  const int lrow = lane >> 2, lk = lane & 3;
  // B) zg[16 x 128] = h2 @ W1^T, K=1024
  v_f32x4 acc[2];
  #pragma unroll
  for (int j = 0; j < 2; j++)
    #pragma unroll
    for (int r = 0; r < 4; r++) acc[j][r] = 0.0f;
  for (int kt = 0; kt < 32; kt++) {
    gl_lds16(W1 + (size_t)(w * 32 + lrow) * 1024 + kt * 32 + lk * 8, Bs + (w * 32) * 32);
    gl_lds16(W1 + (size_t)(w * 32 + 16 + lrow) * 1024 + kt * 32 + lk * 8, Bs + (w * 32 + 16) * 32);
    __syncthreads();
    v_bf16x8 af = *(const v_bf16x8*)&h2S[c * 1032 + kt * 32 + quad * 8];
    #pragma unroll
    for (int j = 0; j < 2; j++) {
      v_bf16x8 bfw = *(const v_bf16x8*)&Bs[(w * 32 + j * 16 + c) * 32 + quad * 8];
      acc[j] = __builtin_amdgcn_mfma_f32_16x16x32_bf16(af, bfw, acc[j], 0, 0, 0);
    }
    __syncthreads();
  }
  // C) write zg tile to LDS
  #pragma unroll
  for (int j = 0; j < 2; j++)
    #pragma unroll
    for (int r = 0; r < 4; r++)
      zgSu[(quad * 4 + r) * 136 + w * 32 + j * 16 + c] = f2b(acc[j][r]);
  __syncthreads();

  // D) P2[16 x 128] = zg[:, 0:64] @ W2^T, K=64
  v_f32x4 acc2[2];
  #pragma unroll
  for (int j = 0; j < 2; j++)
    #pragma unroll
    for (int r = 0; r < 4; r++) acc2[j][r] = 0.0f;
  for (int kt = 0; kt < 2; kt++) {
    gl_lds16(W2 + (size_t)(w * 32 + lrow) * 64 + kt * 32 + lk * 8, Bs + (w * 32) * 32);
    gl_lds16(W2 + (size_t)(w * 32 + 16 + lrow) * 64 + kt * 32 + lk * 8, Bs + (w * 32 + 16) * 32);
    __syncthreads();
    v_bf16x8 af = *(const v_bf16x8*)&zgS[c * 136 + kt * 32 + quad * 8];
    #pragma unroll
    for (int j = 0; j < 2; j++) {
      v_bf16x8 bfw = *(const v_bf16x8*)&Bs[(w * 32 + j * 16 + c) * 32 + quad * 8];
      acc2[j] = __builtin_amdgcn_mfma_f32_16x16x32_bf16(af, bfw, acc2[j], 0, 0, 0);
    }
    __syncthreads();
  }

  // E) epilogue
  #pragma unroll
  for (int j = 0; j < 2; j++)
    #pragma unroll
    for (int r = 0; r < 4; r++) {
      const int row = quad * 4 + r;
      const int col = w * 32 + j * 16 + c;
      const size_t grow = (size_t)(m0 + row);
      if (w < 2) {  // col in [0,64)
        float z = b2f(zgSu[row * 136 + col]);
        float a = acc2[j][r] + dt_b[col];
        float dt = (a > 20.0f) ? a : log1pf(__expf(a));
        dt_a[grow * NSC + col] = dt;
        dtz_a[grow * NSC + col] = dt * z;
      } else {      // col in [64,128)
        P2[grow * 128 + col] = acc2[j][r];
        float g = b2f(zgSu[row * 136 + col]);
        gate_a[grow * NSC + (col - 64)] = g / (1.0f + __expf(-g));
      }
    }
}

// ---------------- chunked parallel scan ----------------
__global__ __launch_bounds__(256) void scanA_kernel(
    const float* __restrict__ dt_a, const float* __restrict__ dtz_a,
    const float* __restrict__ P2, const float* __restrict__ A_log,
    float* __restrict__ Pbuf, float* __restrict__ Sbuf) {
  __shared__ float dtS[CLEN * 16], dtzS[CLEN * 16], biS[CLEN * 16];
  const int k = blockIdx.x, scg = blockIdx.y, b = blockIdx.z;
  const int tid = threadIdx.x;
  const int t0 = k * CLEN;
  {
    int r = tid >> 2, c4 = (tid & 3) * 4;
    *(v_f32x4*)&dtS[r * 16 + c4]  = *(const v_f32x4*)&dt_a[(size_t)(b * NT + t0 + r) * NSC + scg * 16 + c4];
    *(v_f32x4*)&dtzS[r * 16 + c4] = *(const v_f32x4*)&dtz_a[(size_t)(b * NT + t0 + r) * NSC + scg * 16 + c4];
    *(v_f32x4*)&biS[r * 16 + c4]  = *(const v_f32x4*)&P2[(size_t)(b * NT + t0 + r) * 128 + 64 + c4];
  }
  __syncthreads();
  const int st = tid & 15, scl = tid >> 4;
  const float A = -__expf(A_log[(scg * 16 + scl) * NST + st]);
  float P = 1.0f, s = 0.0f;
  #pragma unroll
  for (int t = 0; t < CLEN; t++) {
    float a = fmaf(dtS[t * 16 + scl], A, 1.0f);
    float u = dtzS[t * 16 + scl] * biS[t * 16 + st];
    P *= a;
    s = fmaf(a, s, u);
  }
  size_t idx = (size_t)(b * NCHUNK + k) * 1024 + scg * 256 + tid;
  Pbuf[idx] = P;
  Sbuf[idx] = s;
}

// scanC with scanB folded in: each block redoes the <=31-step prefix combine
__global__ __launch_bounds__(256) void scanC_kernel(
    const float* __restrict__ dt_a, const float* __restrict__ dtz_a,
    const float* __restrict__ P2, const float* __restrict__ gate_a,
    const float* __restrict__ A_log, const float* __restrict__ Pbuf,
    const float* __restrict__ Sbuf, bf16* __restrict__ ys) {
  __shared__ float dtS[CLEN * 16], dtzS[CLEN * 16], biS[CLEN * 16], ciS[CLEN * 16], gS[CLEN * 16];
  const int k = blockIdx.x, scg = blockIdx.y, b = blockIdx.z;
  const int tid = threadIdx.x;
  const int t0 = k * CLEN;
  {
    int r = tid >> 2, c4 = (tid & 3) * 4;
    *(v_f32x4*)&dtS[r * 16 + c4]  = *(const v_f32x4*)&dt_a[(size_t)(b * NT + t0 + r) * NSC + scg * 16 + c4];
    *(v_f32x4*)&dtzS[r * 16 + c4] = *(const v_f32x4*)&dtz_a[(size_t)(b * NT + t0 + r) * NSC + scg * 16 + c4];
    *(v_f32x4*)&biS[r * 16 + c4]  = *(const v_f32x4*)&P2[(size_t)(b * NT + t0 + r) * 128 + 64 + c4];
    *(v_f32x4*)&ciS[r * 16 + c4]  = *(const v_f32x4*)&P2[(size_t)(b * NT + t0 + r) * 128 + 80 + c4];
    *(v_f32x4*)&gS[r * 16 + c4]   = *(const v_f32x4*)&gate_a[(size_t)(b * NT + t0 + r) * NSC + scg * 16 + c4];
  }
  const int st = tid & 15, scl = tid >> 4;
  const float A = -__expf(A_log[(scg * 16 + scl) * NST + st]);
  float s = 0.0f;
  for (int kk = 0; kk < k; kk++) {
    size_t idx = (size_t)(b * NCHUNK + kk) * 1024 + scg * 256 + tid;
    s = fmaf(Pbuf[idx], s, Sbuf[idx]);
  }
  __syncthreads();
  for (int t = 0; t < CLEN; t++) {
    float a = fmaf(dtS[t * 16 + scl], A, 1.0f);
    float u = dtzS[t * 16 + scl] * biS[t * 16 + st];
    s = fmaf(a, s, u);
    float pv = s * ciS[t * 16 + st];
    pv += __shfl_xor(pv, 1, 64);
    pv += __shfl_xor(pv, 2, 64);
    pv += __shfl_xor(pv, 4, 64);
    pv += __shfl_xor(pv, 8, 64);
    if (st == 0)
      ys[(size_t)(b * NT + t0 + t) * NSC + scg * 16 + scl] = __float2bfloat16(pv * gS[t * 16 + scl]);
  }
}

extern "C" void kernel_launch(void* const* d_in, const int* in_sizes, int n_in,
                              void* d_out, int out_size, void* d_ws, size_t ws_size,
                              hipStream_t stream) {
  const float* x      = (const float*)d_in[0];
  const float* qkv_w  = (const float*)d_in[1];
  const float* o_w    = (const float*)d_in[2];
  const float* n1w    = (const float*)d_in[3];
  const float* n2w    = (const float*)d_in[4];
  const float* in_w   = (const float*)d_in[5];
  const float* out_w  = (const float*)d_in[6];
  const float* A_log  = (const float*)d_in[7];
  const float* Bp_w   = (const float*)d_in[8];
  const float* Cp_w   = (const float*)d_in[9];
  const float* dt_w   = (const float*)d_in[10];
  const float* dt_b   = (const float*)d_in[11];
  const float* gate_w = (const float*)d_in[12];
  float* out = (float*)d_out;

  char* ws = (char*)d_ws;
  size_t off = 0;
  auto alloc = [&](size_t bytes) {
    char* p = ws + off;
    off += (bytes + 255) & ~(size_t)255;
    return p;
  };
  bf16* qkvw_b = (bf16*)alloc((size_t)3 * ND * ND * 2);
  bf16* ow_b   = (bf16*)alloc((size_t)ND * ND * 2);
  bf16* outw_b = (bf16*)alloc((size_t)ND * NSC * 2);
  bf16* W1     = (bf16*)alloc((size_t)128 * ND * 2);
  bf16* W2     = (bf16*)alloc((size_t)128 * NSC * 2);
  char* region0 = alloc((size_t)NM * 3 * ND * 2);         // qkv bf16 -> x1 f32
  char* region1 = alloc((size_t)NM * ND * 2);             // h -> attnout
  bf16* VtG    = (bf16*)alloc((size_t)NB * NH * 64 * NT * 2);
  float* P2    = (float*)alloc((size_t)NM * 128 * 4);
  float* dt_a  = (float*)alloc((size_t)NM * NSC * 4);
  float* dtz_a = (float*)alloc((size_t)NM * NSC * 4);
  float* gate_a= (float*)alloc((size_t)NM * NSC * 4);
  bf16*  ys    = (bf16*)alloc((size_t)NM * NSC * 2);
  float* Pbuf  = (float*)alloc((size_t)NB * NCHUNK * 1024 * 4);
  float* Sbuf  = (float*)alloc((size_t)NB * NCHUNK * 1024 * 4);

  bf16*  qkv     = (bf16*)region0;
  float* x1      = (float*)region0;   // aliases qkv (dead after attn)
  bf16*  h       = (bf16*)region1;
  bf16*  attnout = (bf16*)region1;    // aliases h (dead after qkv gemm)

  cvt_rms_kernel<<<4295 + NM, 256, 0, stream>>>(qkv_w, o_w, out_w, in_w, gate_w, dt_w,
                                                Bp_w, Cp_w, qkvw_b, ow_b, outw_b, W1, W2,
                                                x, n1w, h);
  gemm_bt_kernel<false, false><<<dim3(3 * ND / 128, NM / 128), 256, 0, stream>>>(
      h, qkvw_b, nullptr, (void*)qkv, 3 * ND, ND, ND);
  vtrans_kernel<<<dim3(NT / 64, NB * NH), 256, 0, stream>>>(qkv, VtG);
  attn_kernel<<<(NT / 64) * NB * NH, 256, 0, stream>>>(qkv, VtG, attnout);
  gemm_bt64_kernel<true, true><<<dim3(ND / 128, NM / 64), 256, 0, stream>>>(
      attnout, ow_b, x, (void*)x1, ND, ND, ND);
  proj_scan_kernel<<<NM / 16, 256, 0, stream>>>(x1, n2w, W1, W2, dt_b,
                                                dt_a, dtz_a, gate_a, P2);
  scanA_kernel<<<dim3(NCHUNK, 4, NB), 256, 0, stream>>>(dt_a, dtz_a, P2, A_log, Pbuf, Sbuf);
  scanC_kernel<<<dim3(NCHUNK, 4, NB), 256, 0, stream>>>(dt_a, dtz_a, P2, gate_a, A_log,
                                                        Pbuf, Sbuf, ys);
  gemm_bt64_kernel<true, true><<<dim3(ND / 128, NM / 64), 256, 0, stream>>>(
      ys, outw_b, x1, (void*)out, ND, NSC, NSC);
}